// Round 1
// baseline (414.550 us; speedup 1.0000x reference)
//
#include <hip/hip_runtime.h>

// PartialGConv: partial temporal conv (TK=9, pad 4) + mask-ratio + graph einsum.
// Strategy: bf16 implicit-GEMM via MFMA 16x16x32, split conv-GEMM / contraction.
//
// ws layout (bytes), total 51,830,784 (assumes ws_size >= ~50MB):
//   xm   u16[32][64][6400]   @0          x*mask in bf16
//   wb   u16[192][576]       @26,214,400 weights bf16, k=dt*64+cin, 16B-slot swizzled
//   msum f32[32][6400]       @26,435,584 sum_cin mask
//   s    f32[32][6400]       @27,254,784 576/(upd+eps)*uc^2
//   mr   f32[32][6400]       @28,073,984 mask_ratio
//   mb   f32[32][6400]       @28,893,184 m_bool
//   Bc   f32[32][3][256][25] @29,712,384 sum_v uc*A[k,v,w]
//   Cs   u16[8][192][6400]   @32,169,984 raw*s bf16 (per-quarter)

typedef unsigned short u16;
typedef unsigned int u32;
typedef short short8 __attribute__((ext_vector_type(8)));
typedef float f32x4 __attribute__((ext_vector_type(4)));

#define TV 6400
#define KC 192
#define KDIM 576
#define Y_SIZE 13107200
#define MB_OFF 13109075   // Y_SIZE + 1875

#define OFF_WB   26214400
#define OFF_MSUM 26435584
#define OFF_S    27254784
#define OFF_MR   28073984
#define OFF_MB   28893184
#define OFF_BC   29712384
#define OFF_CS   32169984

__device__ __forceinline__ u16 f2bf(float f) {
  u32 u = __builtin_bit_cast(u32, f);
  u = (u + 0x7FFFu + ((u >> 16) & 1u)) >> 16;   // RTNE
  return (u16)u;
}
__device__ __forceinline__ float bf2f(u16 h) {
  return __builtin_bit_cast(float, (u32)h << 16);
}

// ---- xm = bf16(x*mask), float4-vectorized -----------------------------------
__global__ void k_xm(const float* __restrict__ x, const float* __restrict__ mask,
                     u16* __restrict__ xm) {
  int i = blockIdx.x * 256 + threadIdx.x;      // float4 units, 3,276,800 total
  if (i >= 3276800) return;
  float4 xv = ((const float4*)x)[i];
  float4 mv = ((const float4*)mask)[i];
  ushort4 r;
  r.x = f2bf(xv.x * mv.x); r.y = f2bf(xv.y * mv.y);
  r.z = f2bf(xv.z * mv.z); r.w = f2bf(xv.w * mv.w);
  ((ushort4*)xm)[i] = r;
}

// ---- msum[n][tv] = sum_cin mask ---------------------------------------------
__global__ void k_msum(const float* __restrict__ mask, float* __restrict__ msum) {
  int i = blockIdx.x * 256 + threadIdx.x;      // 204800
  if (i >= 204800) return;
  int n = i / TV, tv = i % TV;
  const float* p = mask + (size_t)n * 64 * TV + tv;
  float acc = 0.f;
  for (int cin = 0; cin < 64; ++cin) acc += p[(size_t)cin * TV];
  msum[i] = acc;
}

// ---- wb[kc][k=dt*64+cin], bf16, 16B-slot XOR pre-swizzle (by (kc>>1)&3) -----
__global__ void k_w(const float* __restrict__ weight, u16* __restrict__ wb) {
  int i = blockIdx.x * 256 + threadIdx.x;      // 110592
  if (i >= 110592) return;
  int kc = i / KDIM, k = i % KDIM;
  int cin = k & 63, dt = k >> 6;
  float v = weight[(kc * 64 + cin) * 9 + dt];
  int phys = (k & ~31) | ((((k >> 3) & 3) ^ ((kc >> 1) & 3)) << 3) | (k & 7);
  wb[kc * KDIM + phys] = f2bf(v);
}

// ---- per (n,t): upd -> s, mask_ratio, m_bool, Bc ----------------------------
__global__ void k_prep(const float* __restrict__ msum, const float* __restrict__ A_g,
                       float* __restrict__ s_ws, float* __restrict__ mr_ws,
                       float* __restrict__ mb_ws, float* __restrict__ Bc_ws) {
  int b = blockIdx.x;                          // 8192 = n*256 + t
  int n = b >> 8, t = b & 255;
  int tid = threadIdx.x;                       // 64
  __shared__ float uc[25];
  if (tid < 25) {
    float upd = 0.f;
    for (int dt = 0; dt < 9; ++dt) {
      int tt = t + dt - 4;
      if (tt >= 0 && tt < 256) upd += msum[n * TV + tt * 25 + tid];
    }
    float u_c = fminf(fmaxf(upd, 0.f), 1.f);
    float ratio = 576.f / (upd + 1e-8f);
    s_ws[n * TV + t * 25 + tid] = ratio * u_c * u_c;  // coeff of raw in out
    uc[tid] = u_c;
  }
  __syncthreads();
  if (tid < 25) {
    int w = tid;
    float M = 0.f;
    for (int k = 0; k < 3; ++k) {
      float acc = 0.f;
      for (int v = 0; v < 25; ++v) acc += uc[v] * A_g[(k * 25 + v) * 25 + w];
      Bc_ws[((size_t)(n * 3 + k) * 256 + t) * 25 + w] = acc;
      M += acc;
    }
    float mbv = (M != 0.f) ? 1.f : 0.f;
    mr_ws[n * TV + t * 25 + w] = mbv / (M + 1e-8f);
    mb_ws[n * TV + t * 25 + w] = mbv;
  }
}

// ---- implicit-GEMM: Cs[nl][kc][tv] = bf16( (W x im2col(xm)) * s ) -----------
// BM=96 (2 M-blocks), BN=256, BK=32; 8 waves in 2(M)x4(N) grid; 3x4 tiles/wave.
__global__ __launch_bounds__(512, 4) void k_gemm(
    const u16* __restrict__ xm, const u16* __restrict__ wb,
    const float* __restrict__ s_g, u16* __restrict__ Cs, int n0) {
  __shared__ u16 Al[2][96 * 32];
  __shared__ u16 Bl[2][256 * 32];

  const int tid = threadIdx.x;
  const int bm = blockIdx.x, bn = blockIdx.y, nl = blockIdx.z;
  const int n = n0 + nl;
  const int tv0 = bn * 256;
  const int lane = tid & 63, wid = tid >> 6;
  const int wm = wid >> 2, wn = wid & 3;
  const int lrow = lane & 15, lgrp = lane >> 4;

  const u16* xmn = xm + (size_t)n * 64 * TV;

  f32x4 acc[3][4] = {};

  auto stageA = [&](int buf, int ks) {
    if (tid < 96 * 4) {
      int row = tid >> 2, g = tid & 3;
      uint4 v = *(const uint4*)(wb + (size_t)(bm * 96 + row) * KDIM + ks * 32 + g * 8);
      *(uint4*)&Al[buf][row * 32 + g * 8] = v;
    }
  };
  auto stageB = [&](int buf, int ks) {
    const int dt = ks >> 1, cin0 = (ks & 1) * 32;
    const int shift = tv0 + (dt - 4) * 25;
#pragma unroll
    for (int i = 0; i < 2; ++i) {
      int task = tid + i * 512;                // 1024 = 256 cols x 4 k-chunks
      int col = task & 255, g = task >> 8;
      int tvp = shift + col;                   // im2col: contiguous shift, OOB->0
      bool ok = (tvp >= 0) && (tvp < TV);
      const u16* src = xmn + (size_t)(cin0 + g * 8) * TV + tvp;
      u32 u[4];
#pragma unroll
      for (int j = 0; j < 4; ++j) {
        u32 lo = ok ? (u32)src[(size_t)(2 * j) * TV] : 0u;
        u32 hi = ok ? (u32)src[(size_t)(2 * j + 1) * TV] : 0u;
        u[j] = lo | (hi << 16);
      }
      int phys = g ^ ((col >> 1) & 3);         // match read-side swizzle
      uint4 val; val.x = u[0]; val.y = u[1]; val.z = u[2]; val.w = u[3];
      *(uint4*)&Bl[buf][col * 32 + phys * 8] = val;
    }
  };

  stageA(0, 0);
  stageB(0, 0);
  __syncthreads();

  for (int ks = 0; ks < 18; ++ks) {
    const int cur = ks & 1;
    if (ks < 17) { stageA(cur ^ 1, ks + 1); stageB(cur ^ 1, ks + 1); }
    short8 af[3], bfr[4];
#pragma unroll
    for (int rt = 0; rt < 3; ++rt) {
      int arow = wm * 48 + rt * 16 + lrow;
      af[rt] = *(const short8*)&Al[cur][arow * 32 + ((lgrp ^ ((arow >> 1) & 3)) << 3)];
    }
#pragma unroll
    for (int ct = 0; ct < 4; ++ct) {
      int bcol = wn * 64 + ct * 16 + lrow;
      bfr[ct] = *(const short8*)&Bl[cur][bcol * 32 + ((lgrp ^ ((bcol >> 1) & 3)) << 3)];
    }
#pragma unroll
    for (int rt = 0; rt < 3; ++rt)
#pragma unroll
      for (int ct = 0; ct < 4; ++ct)
        acc[rt][ct] = __builtin_amdgcn_mfma_f32_16x16x32_bf16(af[rt], bfr[ct], acc[rt][ct], 0, 0, 0);
    __syncthreads();
  }

#pragma unroll
  for (int ct = 0; ct < 4; ++ct) {
    int colg = tv0 + wn * 64 + ct * 16 + lrow;
    float sv = s_g[n * TV + colg];
#pragma unroll
    for (int rt = 0; rt < 3; ++rt) {
      int rbase = bm * 96 + wm * 48 + rt * 16 + lgrp * 4;
#pragma unroll
      for (int r = 0; r < 4; ++r)
        Cs[(size_t)(nl * KC + rbase + r) * TV + colg] = f2bf(acc[rt][ct][r] * sv);
    }
  }
}

// ---- contraction: y = (sum_{k,v} Cs*A + sum_k bias*Bc) * mask_ratio ---------
// block = (tg of 8 t, nl); thread = (c, t_local) with 25-w accumulator in VGPRs
__global__ __launch_bounds__(512) void k_contract(
    const u16* __restrict__ Cs, const float* __restrict__ A_g,
    const float* __restrict__ Bc_g, const float* __restrict__ mr_g,
    const float* __restrict__ mb_g, const float* __restrict__ bias_g,
    float* __restrict__ out, int n0) {
  __shared__ u16 Cl[64][210];                 // pad 200->210: stride 105 dw, gcd(105,32)=1
  __shared__ float As[3][25][28];             // pad 25->28 for float4 reads
  __shared__ float Bcs[3][8][25];
  __shared__ float mrs[8][25];
  __shared__ float mbs[8][25];
  __shared__ float biass[192];

  const int tid = threadIdx.x;
  const int tg = blockIdx.x;                  // 0..31
  const int nl = blockIdx.y;                  // 0..7
  const int n = n0 + nl;

  for (int i = tid; i < 3 * 25 * 28; i += 512) {
    int k = i / 700, r = (i % 700) / 28, w = i % 28;
    As[k][r][w] = (w < 25) ? A_g[(k * 25 + r) * 25 + w] : 0.f;
  }
  for (int i = tid; i < 600; i += 512) {
    int k = i / 200, t = (i % 200) / 25, w = i % 25;
    Bcs[k][t][w] = Bc_g[((size_t)(n * 3 + k) * 256 + tg * 8 + t) * 25 + w];
  }
  for (int i = tid; i < 200; i += 512) {
    mrs[i / 25][i % 25] = mr_g[n * TV + tg * 200 + i];
    mbs[i / 25][i % 25] = mb_g[n * TV + tg * 200 + i];
  }
  if (tid < 192) biass[tid] = bias_g[tid];

  const int c = tid & 63, tl = tid >> 6;
  f32x4 a4[7] = {};

  for (int k = 0; k < 3; ++k) {
    __syncthreads();
    for (int i = tid; i < 64 * 100; i += 512) {   // stage 64 rows x 200 cols (dwords)
      int row = i / 100, c2 = i % 100;
      u32 v = *(const u32*)(Cs + (size_t)(nl * KC + k * 64 + row) * TV + tg * 200 + c2 * 2);
      *(u32*)&Cl[row][c2 * 2] = v;
    }
    __syncthreads();
#pragma unroll 5
    for (int v = 0; v < 25; ++v) {
      float cs = bf2f(Cl[c][tl * 25 + v]);
      const f32x4* ar = (const f32x4*)&As[k][v][0];   // broadcast reads
#pragma unroll
      for (int q = 0; q < 7; ++q) a4[q] += cs * ar[q];
    }
  }

  const int t = tg * 8 + tl;
  const size_t obase = ((size_t)(n * 64 + c) * 256 + t) * 25;
  const float b0 = biass[c], b1 = biass[64 + c], b2 = biass[128 + c];
#pragma unroll
  for (int w = 0; w < 25; ++w) {
    float bt = b0 * Bcs[0][tl][w] + b1 * Bcs[1][tl][w] + b2 * Bcs[2][tl][w];
    float y = (a4[w >> 2][w & 3] + bt) * mrs[tl][w];
    out[obase + w] = y;
    out[MB_OFF + obase + w] = mbs[tl][w];
  }
}

extern "C" void kernel_launch(void* const* d_in, const int* in_sizes, int n_in,
                              void* d_out, int out_size, void* d_ws, size_t ws_size,
                              hipStream_t stream) {
  const float* x      = (const float*)d_in[0];
  const float* A      = (const float*)d_in[1];
  const float* mask   = (const float*)d_in[2];
  const float* weight = (const float*)d_in[3];
  const float* bias   = (const float*)d_in[4];
  float* out = (float*)d_out;
  char* ws = (char*)d_ws;

  u16*   xm    = (u16*)(ws);
  u16*   wb    = (u16*)(ws + OFF_WB);
  float* msum  = (float*)(ws + OFF_MSUM);
  float* s_ws  = (float*)(ws + OFF_S);
  float* mr_ws = (float*)(ws + OFF_MR);
  float* mb_ws = (float*)(ws + OFF_MB);
  float* Bc_ws = (float*)(ws + OFF_BC);
  u16*   Cs    = (u16*)(ws + OFF_CS);

  k_xm<<<12800, 256, 0, stream>>>(x, mask, xm);
  k_msum<<<800, 256, 0, stream>>>(mask, msum);
  k_w<<<432, 256, 0, stream>>>(weight, wb);
  k_prep<<<8192, 64, 0, stream>>>(msum, A, s_ws, mr_ws, mb_ws, Bc_ws);

  hipMemcpyAsync(out + Y_SIZE, A, 1875 * sizeof(float),
                 hipMemcpyDeviceToDevice, stream);

  for (int q = 0; q < 4; ++q) {               // quarter the Cs footprint in ws
    k_gemm<<<dim3(2, 25, 8), 512, 0, stream>>>(xm, wb, s_ws, Cs, q * 8);
    k_contract<<<dim3(32, 8), 512, 0, stream>>>(Cs, A, Bc_ws, mr_ws, mb_ws, bias,
                                                out, q * 8);
  }
}

// Round 2
// 255.176 us; speedup vs baseline: 1.6246x; 1.6246x over previous
//
#include <hip/hip_runtime.h>

// PartialGConv: partial temporal conv (TK=9, pad 4) + mask-ratio + graph einsum.
// bf16 implicit-GEMM via MFMA 16x16x32; global_load_lds(16B) staging from a
// channel-last padded xmT layout; split conv-GEMM / contraction.
//
// ws layout (bytes):
//   xmT  u16[32][6600][64]  @0          x*mask bf16, channel-last, 100-row zero pads
//   wb   u16[192][576]      @27,033,600 weights bf16, k=dt*64+cin, 16B-slot swizzled
//   msum f32[32][6400]      @27,254,784 sum_cin mask
//   s    f32[32][6400]      @28,073,984 576/(upd+eps)*uc^2
//   mr   f32[32][6400]      @28,893,184 mask_ratio
//   mb   f32[32][6400]      @29,712,384 m_bool
//   Bc   f32[32][3][256][25]@30,531,584 sum_v uc*A[k,v,w]
//   Cs   u16[chunk][192][6400] @32,989,184  raw*s bf16 (chunk adapts to ws_size)

typedef unsigned short u16;
typedef unsigned int u32;
typedef short short8 __attribute__((ext_vector_type(8)));
typedef float f32x4 __attribute__((ext_vector_type(4)));

#define TV 6400
#define KC 192
#define KDIM 576
#define NPADT 6600          // 100 + 6400 + 100
#define Y_SIZE 13107200
#define MB_OFF 13109075     // Y_SIZE + 1875

#define OFF_WB   27033600
#define OFF_MSUM 27254784
#define OFF_S    28073984
#define OFF_MR   28893184
#define OFF_MB   29712384
#define OFF_BC   30531584
#define OFF_CS   32989184
#define CS_PER_N 2457600    // 192*6400*2

__device__ __forceinline__ u16 f2bf(float f) {
  u32 u = __builtin_bit_cast(u32, f);
  u = (u + 0x7FFFu + ((u >> 16) & 1u)) >> 16;   // RTNE
  return (u16)u;
}
__device__ __forceinline__ float bf2f(u16 h) {
  return __builtin_bit_cast(float, (u32)h << 16);
}
__device__ __forceinline__ void gload_lds16(const u16* g, u16* l) {
  __builtin_amdgcn_global_load_lds(
      (const __attribute__((address_space(1))) u32*)(const void*)g,
      (__attribute__((address_space(3))) u32*)(void*)l, 16, 0, 0);
}

// ---- zero the temporal pad rows of xmT --------------------------------------
__global__ void k_pad(u16* __restrict__ xmT) {
  int i = blockIdx.x * 256 + threadIdx.x;       // 51200 uint4
  if (i >= 51200) return;
  int n = i / 1600, r = i % 1600;               // 200 pad rows x 8 uint4
  int row = r >> 3, c = r & 7;
  int tvrow = (row < 100) ? row : (6400 + row); // front pad / back pad
  uint4 z; z.x = z.y = z.z = z.w = 0u;
  *(uint4*)(xmT + ((size_t)n * NPADT + tvrow) * 64 + c * 8) = z;
}

// ---- xmT = bf16(x*mask) channel-last + msum = sum_cin mask -------------------
__global__ void k_xmT(const float* __restrict__ x, const float* __restrict__ mask,
                      u16* __restrict__ xmT, float* __restrict__ msum) {
  const int tvb = blockIdx.x, n = blockIdx.y;   // grid (100, 32), block 256
  const int tvl = threadIdx.x & 63, q = threadIdx.x >> 6;  // 4 chunks of 16 cin
  const int tv = tvb * 64 + tvl;
  const float* xp = x + ((size_t)n * 64 + q * 16) * TV + tv;
  const float* mp = mask + ((size_t)n * 64 + q * 16) * TV + tv;
  u16 vals[16];
  float msacc = 0.f;
#pragma unroll
  for (int j = 0; j < 16; ++j) {                // coalesced: lanes = consecutive tv
    float xv = xp[(size_t)j * TV];
    float mv = mp[(size_t)j * TV];
    msacc += mv;
    vals[j] = f2bf(xv * mv);
  }
  u16* dst = xmT + ((size_t)n * NPADT + 100 + tv) * 64 + q * 16;
  uint4 lo, hi;
  lo.x = vals[0] | ((u32)vals[1] << 16);  lo.y = vals[2] | ((u32)vals[3] << 16);
  lo.z = vals[4] | ((u32)vals[5] << 16);  lo.w = vals[6] | ((u32)vals[7] << 16);
  hi.x = vals[8] | ((u32)vals[9] << 16);  hi.y = vals[10] | ((u32)vals[11] << 16);
  hi.z = vals[12] | ((u32)vals[13] << 16); hi.w = vals[14] | ((u32)vals[15] << 16);
  *(uint4*)dst = lo;
  *(uint4*)(dst + 8) = hi;
  __shared__ float red[4][64];
  red[q][tvl] = msacc;
  __syncthreads();
  if (q == 0) msum[n * TV + tv] = red[0][tvl] + red[1][tvl] + red[2][tvl] + red[3][tvl];
}

// ---- wb[kc][k=dt*64+cin], bf16, 16B-slot XOR pre-swizzle (by (kc>>1)&3) -----
__global__ void k_w(const float* __restrict__ weight, u16* __restrict__ wb) {
  int i = blockIdx.x * 256 + threadIdx.x;      // 110592
  if (i >= 110592) return;
  int kc = i / KDIM, k = i % KDIM;
  int cin = k & 63, dt = k >> 6;
  float v = weight[(kc * 64 + cin) * 9 + dt];
  int phys = (k & ~31) | ((((k >> 3) & 3) ^ ((kc >> 1) & 3)) << 3) | (k & 7);
  wb[kc * KDIM + phys] = f2bf(v);
}

// ---- per (n,t): upd -> s, mask_ratio, m_bool, Bc ----------------------------
__global__ void k_prep(const float* __restrict__ msum, const float* __restrict__ A_g,
                       float* __restrict__ s_ws, float* __restrict__ mr_ws,
                       float* __restrict__ mb_ws, float* __restrict__ Bc_ws) {
  int b = blockIdx.x;                          // 8192 = n*256 + t
  int n = b >> 8, t = b & 255;
  int tid = threadIdx.x;                       // 64
  __shared__ float uc[25];
  if (tid < 25) {
    float upd = 0.f;
    for (int dt = 0; dt < 9; ++dt) {
      int tt = t + dt - 4;
      if (tt >= 0 && tt < 256) upd += msum[n * TV + tt * 25 + tid];
    }
    float u_c = fminf(fmaxf(upd, 0.f), 1.f);
    float ratio = 576.f / (upd + 1e-8f);
    s_ws[n * TV + t * 25 + tid] = ratio * u_c * u_c;  // coeff of raw in out
    uc[tid] = u_c;
  }
  __syncthreads();
  if (tid < 25) {
    int w = tid;
    float M = 0.f;
    for (int k = 0; k < 3; ++k) {
      float acc = 0.f;
      for (int v = 0; v < 25; ++v) acc += uc[v] * A_g[(k * 25 + v) * 25 + w];
      Bc_ws[((size_t)(n * 3 + k) * 256 + t) * 25 + w] = acc;
      M += acc;
    }
    float mbv = (M != 0.f) ? 1.f : 0.f;
    mr_ws[n * TV + t * 25 + w] = mbv / (M + 1e-8f);
    mb_ws[n * TV + t * 25 + w] = mbv;
  }
}

// ---- implicit-GEMM: Cs[nl][kc][tv] = bf16( (W x im2col(xmT)) * s ) ----------
// BM=96, BN=256, BK=32; 8 waves 2(M)x4(N); 3x4 MFMA tiles/wave.
// Staging: global_load_lds width=16, linear LDS; A pre-swizzled in wb,
// B chunk-major [g][256][8] == fragment order (conflict-free ds_read_b128).
__global__ __launch_bounds__(512, 4) void k_gemm(
    const u16* __restrict__ xmT, const u16* __restrict__ wb,
    const float* __restrict__ s_g, u16* __restrict__ Cs, int n0) {
  __shared__ u16 Al[2][96 * 32];
  __shared__ u16 Bl[2][4 * 256 * 8];

  const int tid = threadIdx.x;
  const int bm = blockIdx.x, bn = blockIdx.y, nl = blockIdx.z;
  const int n = n0 + nl;
  const int tv0 = bn * 256;
  const int lane = tid & 63, wid = tid >> 6;
  const int wm = wid >> 2, wn = wid & 3;
  const int lrow = lane & 15, lgrp = lane >> 4;

  const u16* xmn = xmT + (size_t)n * NPADT * 64;   // points at pad start

  f32x4 acc[3][4] = {};

  // 22 issues per K-step: 6 for A (96x32), 16 for B (4 k-chunks x 4 col-groups)
  auto stage = [&](int buf, int ks) {
    const int dt = ks >> 1, cin0 = (ks & 1) * 32;
    const int shiftp = 100 + tv0 + (dt - 4) * 25;  // padded row index base
#pragma unroll
    for (int j = 0; j < 3; ++j) {
      int task = wid + j * 8;
      if (task >= 22) break;                       // wave-uniform
      if (task < 6) {
        int row = task * 16 + (lane >> 2), koff = (lane & 3) * 8;
        const u16* src = wb + (size_t)(bm * 96 + row) * KDIM + ks * 32 + koff;
        gload_lds16(src, &Al[buf][task * 512]);
      } else {
        int bt = task - 6;
        int g = bt >> 2, col = (bt & 3) * 64 + lane;
        const u16* src = xmn + (size_t)(shiftp + col) * 64 + cin0 + g * 8;
        gload_lds16(src, &Bl[buf][bt * 512]);
      }
    }
  };

  stage(0, 0);
  __syncthreads();

  for (int ks = 0; ks < 18; ++ks) {
    const int cur = ks & 1;
    if (ks < 17) stage(cur ^ 1, ks + 1);
    short8 af[3], bfr[4];
#pragma unroll
    for (int rt = 0; rt < 3; ++rt) {
      int arow = wm * 48 + rt * 16 + lrow;
      af[rt] = *(const short8*)&Al[cur][arow * 32 + ((lgrp ^ ((arow >> 1) & 3)) << 3)];
    }
#pragma unroll
    for (int ct = 0; ct < 4; ++ct) {
      int bcol = wn * 64 + ct * 16 + lrow;
      bfr[ct] = *(const short8*)&Bl[cur][(lgrp * 256 + bcol) * 8];
    }
#pragma unroll
    for (int rt = 0; rt < 3; ++rt)
#pragma unroll
      for (int ct = 0; ct < 4; ++ct)
        acc[rt][ct] = __builtin_amdgcn_mfma_f32_16x16x32_bf16(af[rt], bfr[ct], acc[rt][ct], 0, 0, 0);
    __syncthreads();
  }

#pragma unroll
  for (int ct = 0; ct < 4; ++ct) {
    int colg = tv0 + wn * 64 + ct * 16 + lrow;
    float sv = s_g[n * TV + colg];
#pragma unroll
    for (int rt = 0; rt < 3; ++rt) {
      int rbase = bm * 96 + wm * 48 + rt * 16 + lgrp * 4;
#pragma unroll
      for (int r = 0; r < 4; ++r)
        Cs[(size_t)(nl * KC + rbase + r) * TV + colg] = f2bf(acc[rt][ct][r] * sv);
    }
  }
}

// ---- contraction: y = (sum_{k,v} Cs*A + sum_k bias*Bc) * mask_ratio ---------
// block = (tg of 8 t, nl); thread = (c, t_local), 25-w accumulator in VGPRs
__global__ __launch_bounds__(512) void k_contract(
    const u16* __restrict__ Cs, const float* __restrict__ A_g,
    const float* __restrict__ Bc_g, const float* __restrict__ mr_g,
    const float* __restrict__ mb_g, const float* __restrict__ bias_g,
    float* __restrict__ out, int n0) {
  __shared__ u16 Cl[64][210];                 // stride 105 dw, gcd(105,32)=1
  __shared__ float As[3][25][28];             // pad 25->28 for float4 reads
  __shared__ float Bcs[3][8][25];
  __shared__ float mrs[8][25];
  __shared__ float mbs[8][25];
  __shared__ float biass[192];

  const int tid = threadIdx.x;
  const int tg = blockIdx.x;                  // 0..31
  const int nl = blockIdx.y;
  const int n = n0 + nl;

  for (int i = tid; i < 3 * 25 * 28; i += 512) {
    int k = i / 700, r = (i % 700) / 28, w = i % 28;
    As[k][r][w] = (w < 25) ? A_g[(k * 25 + r) * 25 + w] : 0.f;
  }
  for (int i = tid; i < 600; i += 512) {
    int k = i / 200, t = (i % 200) / 25, w = i % 25;
    Bcs[k][t][w] = Bc_g[((size_t)(n * 3 + k) * 256 + tg * 8 + t) * 25 + w];
  }
  for (int i = tid; i < 200; i += 512) {
    mrs[i / 25][i % 25] = mr_g[n * TV + tg * 200 + i];
    mbs[i / 25][i % 25] = mb_g[n * TV + tg * 200 + i];
  }
  if (tid < 192) biass[tid] = bias_g[tid];

  const int c = tid & 63, tl = tid >> 6;
  f32x4 a4[7] = {};

  for (int k = 0; k < 3; ++k) {
    __syncthreads();
    for (int i = tid; i < 1600; i += 512) {   // 64 rows x 25 x 16B, uint4 global reads
      int row = i / 25, c8 = i % 25;
      const uint4 v = *(const uint4*)(Cs + (size_t)(nl * KC + k * 64 + row) * TV + tg * 200 + c8 * 8);
      u32* d = (u32*)&Cl[row][c8 * 8];
      d[0] = v.x; d[1] = v.y; d[2] = v.z; d[3] = v.w;
    }
    __syncthreads();
#pragma unroll 5
    for (int v = 0; v < 25; ++v) {
      float cs = bf2f(Cl[c][tl * 25 + v]);
      const f32x4* ar = (const f32x4*)&As[k][v][0];   // broadcast reads
#pragma unroll
      for (int q = 0; q < 7; ++q) a4[q] += cs * ar[q];
    }
  }

  const int t = tg * 8 + tl;
  const size_t obase = ((size_t)(n * 64 + c) * 256 + t) * 25;
  const float b0 = biass[c], b1 = biass[64 + c], b2 = biass[128 + c];
#pragma unroll
  for (int w = 0; w < 25; ++w) {
    float bt = b0 * Bcs[0][tl][w] + b1 * Bcs[1][tl][w] + b2 * Bcs[2][tl][w];
    float y = (a4[w >> 2][w & 3] + bt) * mrs[tl][w];
    out[obase + w] = y;
    out[MB_OFF + obase + w] = mbs[tl][w];
  }
}

extern "C" void kernel_launch(void* const* d_in, const int* in_sizes, int n_in,
                              void* d_out, int out_size, void* d_ws, size_t ws_size,
                              hipStream_t stream) {
  const float* x      = (const float*)d_in[0];
  const float* A      = (const float*)d_in[1];
  const float* mask   = (const float*)d_in[2];
  const float* weight = (const float*)d_in[3];
  const float* bias   = (const float*)d_in[4];
  float* out = (float*)d_out;
  char* ws = (char*)d_ws;

  u16*   xmT   = (u16*)(ws);
  u16*   wb    = (u16*)(ws + OFF_WB);
  float* msum  = (float*)(ws + OFF_MSUM);
  float* s_ws  = (float*)(ws + OFF_S);
  float* mr_ws = (float*)(ws + OFF_MR);
  float* mb_ws = (float*)(ws + OFF_MB);
  float* Bc_ws = (float*)(ws + OFF_BC);
  u16*   Cs    = (u16*)(ws + OFF_CS);

  // chunk = samples of Cs that fit in remaining ws (>=7 guaranteed by round-1 pass)
  int chunk = 1;
  if (ws_size > (size_t)OFF_CS + CS_PER_N) {
    size_t c = (ws_size - OFF_CS) / CS_PER_N;
    chunk = (c > 32) ? 32 : (int)c;
  }

  k_pad<<<200, 256, 0, stream>>>(xmT);
  k_xmT<<<dim3(100, 32), 256, 0, stream>>>(x, mask, xmT, msum);
  k_w<<<432, 256, 0, stream>>>(weight, wb);
  k_prep<<<8192, 64, 0, stream>>>(msum, A, s_ws, mr_ws, mb_ws, Bc_ws);

  hipMemcpyAsync(out + Y_SIZE, A, 1875 * sizeof(float),
                 hipMemcpyDeviceToDevice, stream);

  for (int done = 0; done < 32;) {
    int g = (32 - done < chunk) ? (32 - done) : chunk;
    k_gemm<<<dim3(2, 25, g), 512, 0, stream>>>(xmT, wb, s_ws, Cs, done);
    k_contract<<<dim3(32, g), 512, 0, stream>>>(Cs, A, Bc_ws, mr_ws, mb_ws, bias,
                                                out, done);
    done += g;
  }
}

// Round 3
// 252.424 us; speedup vs baseline: 1.6423x; 1.0109x over previous
//
#include <hip/hip_runtime.h>

// PartialGConv: partial temporal conv (TK=9, pad 4) + mask-ratio + graph einsum.
// bf16 implicit-GEMM via MFMA 16x16x32; global_load_lds(16B) staging from a
// channel-last padded xmT layout; depth-2 counted-vmcnt pipeline (T3+T4).
//
// ws layout (bytes):
//   xmT  u16[32][6600][64]  @0          x*mask bf16, channel-last, 100-row zero pads
//   wb   u16[192][576]      @27,033,600 weights bf16, k=dt*64+cin, 16B-slot swizzled
//   msum f32[32][6400]      @27,254,784 sum_cin mask
//   s    f32[32][6400]      @28,073,984 576/(upd+eps)*uc^2
//   mr   f32[32][6400]      @28,893,184 mask_ratio
//   mb   f32[32][6400]      @29,712,384 m_bool
//   Bc   f32[32][3][256][25]@30,531,584 sum_v uc*A[k,v,w]
//   Cs   u16[chunk][192][6400] @32,989,184  raw*s bf16 (chunk adapts to ws_size)

typedef unsigned short u16;
typedef unsigned int u32;
typedef short short8 __attribute__((ext_vector_type(8)));
typedef float f32x4 __attribute__((ext_vector_type(4)));

#define TV 6400
#define KC 192
#define KDIM 576
#define NPADT 6600          // 100 + 6400 + 100
#define Y_SIZE 13107200
#define MB_OFF 13109075     // Y_SIZE + 1875

#define OFF_WB   27033600
#define OFF_MSUM 27254784
#define OFF_S    28073984
#define OFF_MR   28893184
#define OFF_MB   29712384
#define OFF_BC   30531584
#define OFF_CS   32989184
#define CS_PER_N 2457600    // 192*6400*2

#define VMCNT(N) asm volatile("s_waitcnt vmcnt(" #N ")" ::: "memory")

__device__ __forceinline__ u16 f2bf(float f) {
  u32 u = __builtin_bit_cast(u32, f);
  u = (u + 0x7FFFu + ((u >> 16) & 1u)) >> 16;   // RTNE
  return (u16)u;
}
__device__ __forceinline__ float bf2f(u16 h) {
  return __builtin_bit_cast(float, (u32)h << 16);
}
__device__ __forceinline__ void gload_lds16(const u16* g, u16* l) {
  __builtin_amdgcn_global_load_lds(
      (const __attribute__((address_space(1))) u32*)(const void*)g,
      (__attribute__((address_space(3))) u32*)(void*)l, 16, 0, 0);
}

// ---- zero the temporal pad rows of xmT --------------------------------------
__global__ void k_pad(u16* __restrict__ xmT) {
  int i = blockIdx.x * 256 + threadIdx.x;       // 51200 uint4
  if (i >= 51200) return;
  int n = i / 1600, r = i % 1600;               // 200 pad rows x 8 uint4
  int row = r >> 3, c = r & 7;
  int tvrow = (row < 100) ? row : (6400 + row); // front pad / back pad
  uint4 z; z.x = z.y = z.z = z.w = 0u;
  *(uint4*)(xmT + ((size_t)n * NPADT + tvrow) * 64 + c * 8) = z;
}

// ---- xmT = bf16(x*mask) channel-last + msum = sum_cin mask -------------------
__global__ void k_xmT(const float* __restrict__ x, const float* __restrict__ mask,
                      u16* __restrict__ xmT, float* __restrict__ msum) {
  const int tvb = blockIdx.x, n = blockIdx.y;   // grid (100, 32), block 256
  const int tvl = threadIdx.x & 63, q = threadIdx.x >> 6;  // 4 chunks of 16 cin
  const int tv = tvb * 64 + tvl;
  const float* xp = x + ((size_t)n * 64 + q * 16) * TV + tv;
  const float* mp = mask + ((size_t)n * 64 + q * 16) * TV + tv;
  u16 vals[16];
  float msacc = 0.f;
#pragma unroll
  for (int j = 0; j < 16; ++j) {                // coalesced: lanes = consecutive tv
    float xv = xp[(size_t)j * TV];
    float mv = mp[(size_t)j * TV];
    msacc += mv;
    vals[j] = f2bf(xv * mv);
  }
  u16* dst = xmT + ((size_t)n * NPADT + 100 + tv) * 64 + q * 16;
  uint4 lo, hi;
  lo.x = vals[0] | ((u32)vals[1] << 16);  lo.y = vals[2] | ((u32)vals[3] << 16);
  lo.z = vals[4] | ((u32)vals[5] << 16);  lo.w = vals[6] | ((u32)vals[7] << 16);
  hi.x = vals[8] | ((u32)vals[9] << 16);  hi.y = vals[10] | ((u32)vals[11] << 16);
  hi.z = vals[12] | ((u32)vals[13] << 16); hi.w = vals[14] | ((u32)vals[15] << 16);
  *(uint4*)dst = lo;
  *(uint4*)(dst + 8) = hi;
  __shared__ float red[4][64];
  red[q][tvl] = msacc;
  __syncthreads();
  if (q == 0) msum[n * TV + tv] = red[0][tvl] + red[1][tvl] + red[2][tvl] + red[3][tvl];
}

// ---- wb[kc][k=dt*64+cin], bf16, 16B-slot XOR pre-swizzle (by (kc>>1)&3) -----
__global__ void k_w(const float* __restrict__ weight, u16* __restrict__ wb) {
  int i = blockIdx.x * 256 + threadIdx.x;      // 110592
  if (i >= 110592) return;
  int kc = i / KDIM, k = i % KDIM;
  int cin = k & 63, dt = k >> 6;
  float v = weight[(kc * 64 + cin) * 9 + dt];
  int phys = (k & ~31) | ((((k >> 3) & 3) ^ ((kc >> 1) & 3)) << 3) | (k & 7);
  wb[kc * KDIM + phys] = f2bf(v);
}

// ---- per (n,t): upd -> s, mask_ratio, m_bool, Bc ----------------------------
__global__ void k_prep(const float* __restrict__ msum, const float* __restrict__ A_g,
                       float* __restrict__ s_ws, float* __restrict__ mr_ws,
                       float* __restrict__ mb_ws, float* __restrict__ Bc_ws) {
  int b = blockIdx.x;                          // 8192 = n*256 + t
  int n = b >> 8, t = b & 255;
  int tid = threadIdx.x;                       // 64
  __shared__ float uc[25];
  if (tid < 25) {
    float upd = 0.f;
    for (int dt = 0; dt < 9; ++dt) {
      int tt = t + dt - 4;
      if (tt >= 0 && tt < 256) upd += msum[n * TV + tt * 25 + tid];
    }
    float u_c = fminf(fmaxf(upd, 0.f), 1.f);
    float ratio = 576.f / (upd + 1e-8f);
    s_ws[n * TV + t * 25 + tid] = ratio * u_c * u_c;  // coeff of raw in out
    uc[tid] = u_c;
  }
  __syncthreads();
  if (tid < 25) {
    int w = tid;
    float M = 0.f;
    for (int k = 0; k < 3; ++k) {
      float acc = 0.f;
      for (int v = 0; v < 25; ++v) acc += uc[v] * A_g[(k * 25 + v) * 25 + w];
      Bc_ws[((size_t)(n * 3 + k) * 256 + t) * 25 + w] = acc;
      M += acc;
    }
    float mbv = (M != 0.f) ? 1.f : 0.f;
    mr_ws[n * TV + t * 25 + w] = mbv / (M + 1e-8f);
    mb_ws[n * TV + t * 25 + w] = mbv;
  }
}

// ---- implicit-GEMM: Cs[nl][kc][tv] = bf16( (W x im2col(xmT)) * s ) ----------
// BM=96, BN=256, BK=32; 8 waves 2(M)x4(N); 3x4 MFMA tiles/wave.
// Depth-2 counted-vmcnt pipeline: 4-buffer LDS ring, one s_barrier per step,
// waves 0-5 issue 3 global_load_lds/stage -> vmcnt(6); waves 6-7 issue 2 -> vmcnt(4).
__global__ __launch_bounds__(512, 2) void k_gemm(
    const u16* __restrict__ xmT, const u16* __restrict__ wb,
    const float* __restrict__ s_g, u16* __restrict__ Cs, int n0) {
  __shared__ u16 Al[4][96 * 32];      // 24 KB
  __shared__ u16 Bl[4][4 * 256 * 8];  // 64 KB

  const int tid = threadIdx.x;
  const int bm = blockIdx.x, bn = blockIdx.y, nl = blockIdx.z;
  const int n = n0 + nl;
  const int tv0 = bn * 256;
  const int lane = tid & 63, wid = tid >> 6;
  const int wm = wid >> 2, wn = wid & 3;
  const int lrow = lane & 15, lgrp = lane >> 4;

  const u16* xmn = xmT + (size_t)n * NPADT * 64;   // points at pad start

  f32x4 acc[3][4] = {};

  // 22 issues per K-step: 6 for A (96x32), 16 for B (4 k-chunks x 4 col-groups)
  auto stage = [&](int buf, int ks) {
    const int dt = ks >> 1, cin0 = (ks & 1) * 32;
    const int shiftp = 100 + tv0 + (dt - 4) * 25;  // padded row index base
#pragma unroll
    for (int j = 0; j < 3; ++j) {
      int task = wid + j * 8;
      if (task >= 22) break;                       // wave-uniform
      if (task < 6) {
        int row = task * 16 + (lane >> 2), koff = (lane & 3) * 8;
        const u16* src = wb + (size_t)(bm * 96 + row) * KDIM + ks * 32 + koff;
        gload_lds16(src, &Al[buf][task * 512]);
      } else {
        int bt = task - 6;
        int g = bt >> 2, col = (bt & 3) * 64 + lane;
        const u16* src = xmn + (size_t)(shiftp + col) * 64 + cin0 + g * 8;
        gload_lds16(src, &Bl[buf][bt * 512]);
      }
    }
  };

  stage(0, 0);
  stage(1, 1);

  for (int ks = 0; ks < 18; ++ks) {
    const int cur = ks & 3;
    if (ks < 16) stage((ks + 2) & 3, ks + 2);
    // wait for MY stage-ks loads: allow (loads/stage x stages-newer) in flight
    if (ks < 16) {
      if (wid < 6) VMCNT(6); else VMCNT(4);
    } else if (ks == 16) {
      if (wid < 6) VMCNT(3); else VMCNT(2);
    } else {
      VMCNT(0);
    }
    __builtin_amdgcn_s_barrier();      // all waves' stage-ks data now in LDS
    asm volatile("" ::: "memory");     // pin ds_reads behind the barrier

    short8 af[3], bfr[4];
#pragma unroll
    for (int rt = 0; rt < 3; ++rt) {
      int arow = wm * 48 + rt * 16 + lrow;
      af[rt] = *(const short8*)&Al[cur][arow * 32 + ((lgrp ^ ((arow >> 1) & 3)) << 3)];
    }
#pragma unroll
    for (int ct = 0; ct < 4; ++ct) {
      int bcol = wn * 64 + ct * 16 + lrow;
      bfr[ct] = *(const short8*)&Bl[cur][(lgrp * 256 + bcol) * 8];
    }
#pragma unroll
    for (int rt = 0; rt < 3; ++rt)
#pragma unroll
      for (int ct = 0; ct < 4; ++ct)
        acc[rt][ct] = __builtin_amdgcn_mfma_f32_16x16x32_bf16(af[rt], bfr[ct], acc[rt][ct], 0, 0, 0);
    // no trailing barrier: 4-ring guarantees writes at iter ks+1 target
    // buf[(ks+3)&3], disjoint from buf[ks&3] reads within the skew window
  }

#pragma unroll
  for (int ct = 0; ct < 4; ++ct) {
    int colg = tv0 + wn * 64 + ct * 16 + lrow;
    float sv = s_g[n * TV + colg];
#pragma unroll
    for (int rt = 0; rt < 3; ++rt) {
      int rbase = bm * 96 + wm * 48 + rt * 16 + lgrp * 4;
#pragma unroll
      for (int r = 0; r < 4; ++r)
        Cs[(size_t)(nl * KC + rbase + r) * TV + colg] = f2bf(acc[rt][ct][r] * sv);
    }
  }
}

// ---- contraction: y = (sum_{k,v} Cs*A + sum_k bias*Bc) * mask_ratio ---------
// block = (tg of 8 t, nl); thread = (c, t_local), 25-w accumulator in VGPRs
__global__ __launch_bounds__(512) void k_contract(
    const u16* __restrict__ Cs, const float* __restrict__ A_g,
    const float* __restrict__ Bc_g, const float* __restrict__ mr_g,
    const float* __restrict__ mb_g, const float* __restrict__ bias_g,
    float* __restrict__ out, int n0) {
  __shared__ u16 Cl[64][210];                 // stride 105 dw, gcd(105,32)=1
  __shared__ float As[3][25][28];             // pad 25->28 for float4 reads
  __shared__ float Bcs[3][8][25];
  __shared__ float mrs[8][25];
  __shared__ float mbs[8][25];
  __shared__ float biass[192];

  const int tid = threadIdx.x;
  const int tg = blockIdx.x;                  // 0..31
  const int nl = blockIdx.y;
  const int n = n0 + nl;

  for (int i = tid; i < 3 * 25 * 28; i += 512) {
    int k = i / 700, r = (i % 700) / 28, w = i % 28;
    As[k][r][w] = (w < 25) ? A_g[(k * 25 + r) * 25 + w] : 0.f;
  }
  for (int i = tid; i < 600; i += 512) {
    int k = i / 200, t = (i % 200) / 25, w = i % 25;
    Bcs[k][t][w] = Bc_g[((size_t)(n * 3 + k) * 256 + tg * 8 + t) * 25 + w];
  }
  for (int i = tid; i < 200; i += 512) {
    mrs[i / 25][i % 25] = mr_g[n * TV + tg * 200 + i];
    mbs[i / 25][i % 25] = mb_g[n * TV + tg * 200 + i];
  }
  if (tid < 192) biass[tid] = bias_g[tid];

  const int c = tid & 63, tl = tid >> 6;
  f32x4 a4[7] = {};

  for (int k = 0; k < 3; ++k) {
    __syncthreads();
    for (int i = tid; i < 1600; i += 512) {   // 64 rows x 25 x 16B, uint4 global reads
      int row = i / 25, c8 = i % 25;
      const uint4 v = *(const uint4*)(Cs + (size_t)(nl * KC + k * 64 + row) * TV + tg * 200 + c8 * 8);
      u32* d = (u32*)&Cl[row][c8 * 8];
      d[0] = v.x; d[1] = v.y; d[2] = v.z; d[3] = v.w;
    }
    __syncthreads();
#pragma unroll 5
    for (int v = 0; v < 25; ++v) {
      float cs = bf2f(Cl[c][tl * 25 + v]);
      const f32x4* ar = (const f32x4*)&As[k][v][0];   // broadcast reads
#pragma unroll
      for (int q = 0; q < 7; ++q) a4[q] += cs * ar[q];
    }
  }

  const int t = tg * 8 + tl;
  const size_t obase = ((size_t)(n * 64 + c) * 256 + t) * 25;
  const float b0 = biass[c], b1 = biass[64 + c], b2 = biass[128 + c];
#pragma unroll
  for (int w = 0; w < 25; ++w) {
    float bt = b0 * Bcs[0][tl][w] + b1 * Bcs[1][tl][w] + b2 * Bcs[2][tl][w];
    float y = (a4[w >> 2][w & 3] + bt) * mrs[tl][w];
    out[obase + w] = y;
    out[MB_OFF + obase + w] = mbs[tl][w];
  }
}

extern "C" void kernel_launch(void* const* d_in, const int* in_sizes, int n_in,
                              void* d_out, int out_size, void* d_ws, size_t ws_size,
                              hipStream_t stream) {
  const float* x      = (const float*)d_in[0];
  const float* A      = (const float*)d_in[1];
  const float* mask   = (const float*)d_in[2];
  const float* weight = (const float*)d_in[3];
  const float* bias   = (const float*)d_in[4];
  float* out = (float*)d_out;
  char* ws = (char*)d_ws;

  u16*   xmT   = (u16*)(ws);
  u16*   wb    = (u16*)(ws + OFF_WB);
  float* msum  = (float*)(ws + OFF_MSUM);
  float* s_ws  = (float*)(ws + OFF_S);
  float* mr_ws = (float*)(ws + OFF_MR);
  float* mb_ws = (float*)(ws + OFF_MB);
  float* Bc_ws = (float*)(ws + OFF_BC);
  u16*   Cs    = (u16*)(ws + OFF_CS);

  // chunk = samples of Cs that fit in remaining ws
  int chunk = 1;
  if (ws_size > (size_t)OFF_CS + CS_PER_N) {
    size_t c = (ws_size - OFF_CS) / CS_PER_N;
    chunk = (c > 32) ? 32 : (int)c;
  }

  k_pad<<<200, 256, 0, stream>>>(xmT);
  k_xmT<<<dim3(100, 32), 256, 0, stream>>>(x, mask, xmT, msum);
  k_w<<<432, 256, 0, stream>>>(weight, wb);
  k_prep<<<8192, 64, 0, stream>>>(msum, A, s_ws, mr_ws, mb_ws, Bc_ws);

  hipMemcpyAsync(out + Y_SIZE, A, 1875 * sizeof(float),
                 hipMemcpyDeviceToDevice, stream);

  for (int done = 0; done < 32;) {
    int g = (32 - done < chunk) ? (32 - done) : chunk;
    k_gemm<<<dim3(2, 25, g), 512, 0, stream>>>(xmT, wb, s_ws, Cs, done);
    k_contract<<<dim3(32, g), 512, 0, stream>>>(Cs, A, Bc_ws, mr_ws, mb_ws, bias,
                                                out, done);
    done += g;
  }
}

// Round 4
// 227.468 us; speedup vs baseline: 1.8225x; 1.1097x over previous
//
#include <hip/hip_runtime.h>

// PartialGConv: partial temporal conv (TK=9, pad 4) + mask-ratio + graph einsum.
// bf16 implicit-GEMM via MFMA 16x16x32; coalesced global_load_lds(16B) staging
// from a cin-chunk-major padded xmT2 layout; depth-2 counted-vmcnt pipeline.
//
// ws layout (bytes):
//   xmT2 u16[32][8][6600][8] @0          x*mask bf16, cin-chunk-major, 100-row pads
//   wb   u16[192][576]      @27,033,600 weights bf16, k=dt*64+cin, 16B-slot swizzled
//   msum f32[32][6400]      @27,254,784 sum_cin mask
//   s    f32[32][6400]      @28,073,984 576/(upd+eps)*uc^2
//   mr   f32[32][6400]      @28,893,184 mask_ratio
//   mb   f32[32][6400]      @29,712,384 m_bool
//   Bc   f32[32][3][256][25]@30,531,584 sum_v uc*A[k,v,w]
//   Cs   u16[chunk][192][6400] @32,989,184  raw*s bf16 (chunk adapts to ws_size)

typedef unsigned short u16;
typedef unsigned int u32;
typedef short short8 __attribute__((ext_vector_type(8)));
typedef float f32x4 __attribute__((ext_vector_type(4)));

#define TV 6400
#define KC 192
#define KDIM 576
#define NPADT 6600          // 100 + 6400 + 100
#define Y_SIZE 13107200
#define MB_OFF 13109075     // Y_SIZE + 1875

#define OFF_WB   27033600
#define OFF_MSUM 27254784
#define OFF_S    28073984
#define OFF_MR   28893184
#define OFF_MB   29712384
#define OFF_BC   30531584
#define OFF_CS   32989184
#define CS_PER_N 2457600    // 192*6400*2

#define VMCNT(N) asm volatile("s_waitcnt vmcnt(" #N ")" ::: "memory")

__device__ __forceinline__ u16 f2bf(float f) {
  u32 u = __builtin_bit_cast(u32, f);
  u = (u + 0x7FFFu + ((u >> 16) & 1u)) >> 16;   // RTNE
  return (u16)u;
}
__device__ __forceinline__ float bf2f(u16 h) {
  return __builtin_bit_cast(float, (u32)h << 16);
}
__device__ __forceinline__ void gload_lds16(const u16* g, u16* l) {
  __builtin_amdgcn_global_load_lds(
      (const __attribute__((address_space(1))) u32*)(const void*)g,
      (__attribute__((address_space(3))) u32*)(void*)l, 16, 0, 0);
}

// ---- zero the temporal pad rows of xmT2 -------------------------------------
__global__ void k_pad(u16* __restrict__ xmT2) {
  int i = blockIdx.x * 256 + threadIdx.x;       // 51200 uint4
  if (i >= 51200) return;
  int n = i / 1600, r = i % 1600;               // 8 chunks x 200 pad rows
  int c8 = r / 200, row = r % 200;
  int tvrow = (row < 100) ? row : (6400 + row); // front pad / back pad
  uint4 z; z.x = z.y = z.z = z.w = 0u;
  *(uint4*)(xmT2 + (((size_t)n * 8 + c8) * NPADT + tvrow) * 8) = z;
}

// ---- xmT2 = bf16(x*mask) cin-chunk-major + msum = sum_cin mask --------------
__global__ void k_xmT(const float* __restrict__ x, const float* __restrict__ mask,
                      u16* __restrict__ xmT2, float* __restrict__ msum) {
  const int tvb = blockIdx.x, n = blockIdx.y;   // grid (100, 32), block 256
  const int tvl = threadIdx.x & 63, q = threadIdx.x >> 6;  // 4 quads of 16 cin
  const int tv = tvb * 64 + tvl;
  const float* xp = x + ((size_t)n * 64 + q * 16) * TV + tv;
  const float* mp = mask + ((size_t)n * 64 + q * 16) * TV + tv;
  u16 vals[16];
  float msacc = 0.f;
#pragma unroll
  for (int j = 0; j < 16; ++j) {                // coalesced: lanes = consecutive tv
    float xv = xp[(size_t)j * TV];
    float mv = mp[(size_t)j * TV];
    msacc += mv;
    vals[j] = f2bf(xv * mv);
  }
  uint4 lo, hi;
  lo.x = vals[0] | ((u32)vals[1] << 16);  lo.y = vals[2] | ((u32)vals[3] << 16);
  lo.z = vals[4] | ((u32)vals[5] << 16);  lo.w = vals[6] | ((u32)vals[7] << 16);
  hi.x = vals[8] | ((u32)vals[9] << 16);  hi.y = vals[10] | ((u32)vals[11] << 16);
  hi.z = vals[12] | ((u32)vals[13] << 16); hi.w = vals[14] | ((u32)vals[15] << 16);
  // chunk c8 = q*2 (vals 0-7) and q*2+1 (vals 8-15); lanes contiguous in tv
  *(uint4*)(xmT2 + (((size_t)n * 8 + q * 2) * NPADT + 100 + tv) * 8) = lo;
  *(uint4*)(xmT2 + (((size_t)n * 8 + q * 2 + 1) * NPADT + 100 + tv) * 8) = hi;
  __shared__ float red[4][64];
  red[q][tvl] = msacc;
  __syncthreads();
  if (q == 0) msum[n * TV + tv] = red[0][tvl] + red[1][tvl] + red[2][tvl] + red[3][tvl];
}

// ---- wb[kc][k=dt*64+cin], bf16, 16B-slot XOR pre-swizzle (by (kc>>1)&3) -----
__global__ void k_w(const float* __restrict__ weight, u16* __restrict__ wb) {
  int i = blockIdx.x * 256 + threadIdx.x;      // 110592
  if (i >= 110592) return;
  int kc = i / KDIM, k = i % KDIM;
  int cin = k & 63, dt = k >> 6;
  float v = weight[(kc * 64 + cin) * 9 + dt];
  int phys = (k & ~31) | ((((k >> 3) & 3) ^ ((kc >> 1) & 3)) << 3) | (k & 7);
  wb[kc * KDIM + phys] = f2bf(v);
}

// ---- per (n,t): upd -> s, mask_ratio, m_bool, Bc ----------------------------
__global__ void k_prep(const float* __restrict__ msum, const float* __restrict__ A_g,
                       float* __restrict__ s_ws, float* __restrict__ mr_ws,
                       float* __restrict__ mb_ws, float* __restrict__ Bc_ws) {
  int b = blockIdx.x;                          // 8192 = n*256 + t
  int n = b >> 8, t = b & 255;
  int tid = threadIdx.x;                       // 64
  __shared__ float uc[25];
  if (tid < 25) {
    float upd = 0.f;
    for (int dt = 0; dt < 9; ++dt) {
      int tt = t + dt - 4;
      if (tt >= 0 && tt < 256) upd += msum[n * TV + tt * 25 + tid];
    }
    float u_c = fminf(fmaxf(upd, 0.f), 1.f);
    float ratio = 576.f / (upd + 1e-8f);
    s_ws[n * TV + t * 25 + tid] = ratio * u_c * u_c;  // coeff of raw in out
    uc[tid] = u_c;
  }
  __syncthreads();
  if (tid < 25) {
    int w = tid;
    float M = 0.f;
    for (int k = 0; k < 3; ++k) {
      float acc = 0.f;
      for (int v = 0; v < 25; ++v) acc += uc[v] * A_g[(k * 25 + v) * 25 + w];
      Bc_ws[((size_t)(n * 3 + k) * 256 + t) * 25 + w] = acc;
      M += acc;
    }
    float mbv = (M != 0.f) ? 1.f : 0.f;
    mr_ws[n * TV + t * 25 + w] = mbv / (M + 1e-8f);
    mb_ws[n * TV + t * 25 + w] = mbv;
  }
}

// ---- implicit-GEMM: Cs[nl][kc][tv] = bf16( (W x im2col(xmT2)) * s ) ---------
// BM=96, BN=256, BK=32; 8 waves 2(M)x4(N); 3x4 MFMA tiles/wave.
// Depth-2 counted-vmcnt pipeline: 4-buffer LDS ring, one s_barrier per step.
// B staging now fully coalesced: lanes = consecutive tv, 1KB contiguous/issue.
__global__ __launch_bounds__(512, 2) void k_gemm(
    const u16* __restrict__ xmT2, const u16* __restrict__ wb,
    const float* __restrict__ s_g, u16* __restrict__ Cs, int n0) {
  __shared__ u16 Al[4][96 * 32];      // 24 KB
  __shared__ u16 Bl[4][4 * 256 * 8];  // 64 KB

  const int tid = threadIdx.x;
  const int bm = blockIdx.x, bn = blockIdx.y, nl = blockIdx.z;
  const int n = n0 + nl;
  const int tv0 = bn * 256;
  const int lane = tid & 63, wid = tid >> 6;
  const int wm = wid >> 2, wn = wid & 3;
  const int lrow = lane & 15, lgrp = lane >> 4;

  const u16* xmn = xmT2 + (size_t)n * 8 * NPADT * 8;

  f32x4 acc[3][4] = {};

  // 22 issues per K-step: 6 for A (96x32), 16 for B (4 cin-chunks x 4 col-groups)
  auto stage = [&](int buf, int ks) {
    const int dt = ks >> 1, cq = (ks & 1) * 4;
    const int shiftp = 100 + tv0 + (dt - 4) * 25;  // padded row index base
#pragma unroll
    for (int j = 0; j < 3; ++j) {
      int task = wid + j * 8;
      if (task >= 22) break;                       // wave-uniform
      if (task < 6) {
        int row = task * 16 + (lane >> 2), koff = (lane & 3) * 8;
        const u16* src = wb + (size_t)(bm * 96 + row) * KDIM + ks * 32 + koff;
        gload_lds16(src, &Al[buf][task * 512]);
      } else {
        int bt = task - 6;
        int g = bt >> 2, col = (bt & 3) * 64 + lane;
        // contiguous: consecutive lanes (tv) -> consecutive 16B
        const u16* src = xmn + ((size_t)(cq + g) * NPADT + shiftp + col) * 8;
        gload_lds16(src, &Bl[buf][bt * 512]);
      }
    }
  };

  stage(0, 0);
  stage(1, 1);

  for (int ks = 0; ks < 18; ++ks) {
    const int cur = ks & 3;
    if (ks < 16) stage((ks + 2) & 3, ks + 2);
    // wait for MY stage-ks loads: allow (loads/stage x stages-newer) in flight
    if (ks < 16) {
      if (wid < 6) VMCNT(6); else VMCNT(4);
    } else if (ks == 16) {
      if (wid < 6) VMCNT(3); else VMCNT(2);
    } else {
      VMCNT(0);
    }
    __builtin_amdgcn_s_barrier();      // all waves' stage-ks data now in LDS
    asm volatile("" ::: "memory");     // pin ds_reads behind the barrier

    short8 af[3], bfr[4];
#pragma unroll
    for (int rt = 0; rt < 3; ++rt) {
      int arow = wm * 48 + rt * 16 + lrow;
      af[rt] = *(const short8*)&Al[cur][arow * 32 + ((lgrp ^ ((arow >> 1) & 3)) << 3)];
    }
#pragma unroll
    for (int ct = 0; ct < 4; ++ct) {
      int bcol = wn * 64 + ct * 16 + lrow;
      bfr[ct] = *(const short8*)&Bl[cur][(lgrp * 256 + bcol) * 8];
    }
#pragma unroll
    for (int rt = 0; rt < 3; ++rt)
#pragma unroll
      for (int ct = 0; ct < 4; ++ct)
        acc[rt][ct] = __builtin_amdgcn_mfma_f32_16x16x32_bf16(af[rt], bfr[ct], acc[rt][ct], 0, 0, 0);
    // no trailing barrier: 4-ring keeps write buffers disjoint from read buffers
    // within the one-barrier skew window
  }

#pragma unroll
  for (int ct = 0; ct < 4; ++ct) {
    int colg = tv0 + wn * 64 + ct * 16 + lrow;
    float sv = s_g[n * TV + colg];
#pragma unroll
    for (int rt = 0; rt < 3; ++rt) {
      int rbase = bm * 96 + wm * 48 + rt * 16 + lgrp * 4;
#pragma unroll
      for (int r = 0; r < 4; ++r)
        Cs[(size_t)(nl * KC + rbase + r) * TV + colg] = f2bf(acc[rt][ct][r] * sv);
    }
  }
}

// ---- contraction: y = (sum_{k,v} Cs*A + sum_k bias*Bc) * mask_ratio ---------
// block = (tg of 8 t, nl); thread = (c, t_local), 25-w accumulator in VGPRs
__global__ __launch_bounds__(512) void k_contract(
    const u16* __restrict__ Cs, const float* __restrict__ A_g,
    const float* __restrict__ Bc_g, const float* __restrict__ mr_g,
    const float* __restrict__ mb_g, const float* __restrict__ bias_g,
    float* __restrict__ out, int n0) {
  __shared__ u16 Cl[64][210];                 // stride 105 dw, gcd(105,32)=1
  __shared__ float As[3][25][28];             // pad 25->28 for float4 reads
  __shared__ float Bcs[3][8][25];
  __shared__ float mrs[8][25];
  __shared__ float mbs[8][25];
  __shared__ float biass[192];

  const int tid = threadIdx.x;
  const int tg = blockIdx.x;                  // 0..31
  const int nl = blockIdx.y;
  const int n = n0 + nl;

  for (int i = tid; i < 3 * 25 * 28; i += 512) {
    int k = i / 700, r = (i % 700) / 28, w = i % 28;
    As[k][r][w] = (w < 25) ? A_g[(k * 25 + r) * 25 + w] : 0.f;
  }
  for (int i = tid; i < 600; i += 512) {
    int k = i / 200, t = (i % 200) / 25, w = i % 25;
    Bcs[k][t][w] = Bc_g[((size_t)(n * 3 + k) * 256 + tg * 8 + t) * 25 + w];
  }
  for (int i = tid; i < 200; i += 512) {
    mrs[i / 25][i % 25] = mr_g[n * TV + tg * 200 + i];
    mbs[i / 25][i % 25] = mb_g[n * TV + tg * 200 + i];
  }
  if (tid < 192) biass[tid] = bias_g[tid];

  const int c = tid & 63, tl = tid >> 6;
  f32x4 a4[7] = {};

  for (int k = 0; k < 3; ++k) {
    __syncthreads();
    for (int i = tid; i < 1600; i += 512) {   // 64 rows x 25 x 16B, uint4 global reads
      int row = i / 25, c8 = i % 25;
      const uint4 v = *(const uint4*)(Cs + (size_t)(nl * KC + k * 64 + row) * TV + tg * 200 + c8 * 8);
      u32* d = (u32*)&Cl[row][c8 * 8];
      d[0] = v.x; d[1] = v.y; d[2] = v.z; d[3] = v.w;
    }
    __syncthreads();
#pragma unroll 5
    for (int v = 0; v < 25; ++v) {
      float cs = bf2f(Cl[c][tl * 25 + v]);
      const f32x4* ar = (const f32x4*)&As[k][v][0];   // broadcast reads
#pragma unroll
      for (int q = 0; q < 7; ++q) a4[q] += cs * ar[q];
    }
  }

  const int t = tg * 8 + tl;
  const size_t obase = ((size_t)(n * 64 + c) * 256 + t) * 25;
  const float b0 = biass[c], b1 = biass[64 + c], b2 = biass[128 + c];
#pragma unroll
  for (int w = 0; w < 25; ++w) {
    float bt = b0 * Bcs[0][tl][w] + b1 * Bcs[1][tl][w] + b2 * Bcs[2][tl][w];
    float y = (a4[w >> 2][w & 3] + bt) * mrs[tl][w];
    out[obase + w] = y;
    out[MB_OFF + obase + w] = mbs[tl][w];
  }
}

extern "C" void kernel_launch(void* const* d_in, const int* in_sizes, int n_in,
                              void* d_out, int out_size, void* d_ws, size_t ws_size,
                              hipStream_t stream) {
  const float* x      = (const float*)d_in[0];
  const float* A      = (const float*)d_in[1];
  const float* mask   = (const float*)d_in[2];
  const float* weight = (const float*)d_in[3];
  const float* bias   = (const float*)d_in[4];
  float* out = (float*)d_out;
  char* ws = (char*)d_ws;

  u16*   xmT2  = (u16*)(ws);
  u16*   wb    = (u16*)(ws + OFF_WB);
  float* msum  = (float*)(ws + OFF_MSUM);
  float* s_ws  = (float*)(ws + OFF_S);
  float* mr_ws = (float*)(ws + OFF_MR);
  float* mb_ws = (float*)(ws + OFF_MB);
  float* Bc_ws = (float*)(ws + OFF_BC);
  u16*   Cs    = (u16*)(ws + OFF_CS);

  // chunk = samples of Cs that fit in remaining ws
  int chunk = 1;
  if (ws_size > (size_t)OFF_CS + CS_PER_N) {
    size_t c = (ws_size - OFF_CS) / CS_PER_N;
    chunk = (c > 32) ? 32 : (int)c;
  }

  k_pad<<<200, 256, 0, stream>>>(xmT2);
  k_xmT<<<dim3(100, 32), 256, 0, stream>>>(x, mask, xmT2, msum);
  k_w<<<432, 256, 0, stream>>>(weight, wb);
  k_prep<<<8192, 64, 0, stream>>>(msum, A, s_ws, mr_ws, mb_ws, Bc_ws);

  hipMemcpyAsync(out + Y_SIZE, A, 1875 * sizeof(float),
                 hipMemcpyDeviceToDevice, stream);

  for (int done = 0; done < 32;) {
    int g = (32 - done < chunk) ? (32 - done) : chunk;
    k_gemm<<<dim3(2, 25, g), 512, 0, stream>>>(xmT2, wb, s_ws, Cs, done);
    k_contract<<<dim3(32, g), 512, 0, stream>>>(Cs, A, Bc_ws, mr_ws, mb_ws, bias,
                                                out, done);
    done += g;
  }
}

// Round 5
// 217.926 us; speedup vs baseline: 1.9022x; 1.0438x over previous
//
#include <hip/hip_runtime.h>

// PartialGConv: partial temporal conv (TK=9, pad 4) + mask-ratio + graph einsum.
// bf16 implicit-GEMM via MFMA 16x16x32; coalesced global_load_lds(16B) staging
// from a cin-chunk-major padded xmT2 layout; depth-2 counted-vmcnt pipeline.
// k_contract: LDS-transposed coalesced epilogue writes.
//
// ws layout (bytes):
//   xmT2 u16[32][8][6600][8] @0          x*mask bf16, cin-chunk-major, 100-row pads
//   wb   u16[192][576]      @27,033,600 weights bf16, k=dt*64+cin, 16B-slot swizzled
//   msum f32[32][6400]      @27,254,784 sum_cin mask
//   s    f32[32][6400]      @28,073,984 576/(upd+eps)*uc^2
//   mr   f32[32][6400]      @28,893,184 mask_ratio
//   mb   f32[32][6400]      @29,712,384 m_bool
//   Bc   f32[32][3][256][25]@30,531,584 sum_v uc*A[k,v,w]
//   Cs   u16[chunk][192][6400] @32,989,184  raw*s bf16 (chunk adapts to ws_size)

typedef unsigned short u16;
typedef unsigned int u32;
typedef short short8 __attribute__((ext_vector_type(8)));
typedef float f32x4 __attribute__((ext_vector_type(4)));

#define TV 6400
#define KC 192
#define KDIM 576
#define NPADT 6600          // 100 + 6400 + 100
#define Y_SIZE 13107200
#define MB_OFF 13109075     // Y_SIZE + 1875

#define OFF_WB   27033600
#define OFF_MSUM 27254784
#define OFF_S    28073984
#define OFF_MR   28893184
#define OFF_MB   29712384
#define OFF_BC   30531584
#define OFF_CS   32989184
#define CS_PER_N 2457600    // 192*6400*2

#define VMCNT(N) asm volatile("s_waitcnt vmcnt(" #N ")" ::: "memory")

__device__ __forceinline__ u16 f2bf(float f) {
  u32 u = __builtin_bit_cast(u32, f);
  u = (u + 0x7FFFu + ((u >> 16) & 1u)) >> 16;   // RTNE
  return (u16)u;
}
__device__ __forceinline__ float bf2f(u16 h) {
  return __builtin_bit_cast(float, (u32)h << 16);
}
__device__ __forceinline__ void gload_lds16(const u16* g, u16* l) {
  __builtin_amdgcn_global_load_lds(
      (const __attribute__((address_space(1))) u32*)(const void*)g,
      (__attribute__((address_space(3))) u32*)(void*)l, 16, 0, 0);
}

// ---- zero the temporal pad rows of xmT2 -------------------------------------
__global__ void k_pad(u16* __restrict__ xmT2) {
  int i = blockIdx.x * 256 + threadIdx.x;       // 51200 uint4
  if (i >= 51200) return;
  int n = i / 1600, r = i % 1600;               // 8 chunks x 200 pad rows
  int c8 = r / 200, row = r % 200;
  int tvrow = (row < 100) ? row : (6400 + row); // front pad / back pad
  uint4 z; z.x = z.y = z.z = z.w = 0u;
  *(uint4*)(xmT2 + (((size_t)n * 8 + c8) * NPADT + tvrow) * 8) = z;
}

// ---- xmT2 = bf16(x*mask) cin-chunk-major + msum = sum_cin mask --------------
__global__ void k_xmT(const float* __restrict__ x, const float* __restrict__ mask,
                      u16* __restrict__ xmT2, float* __restrict__ msum) {
  const int tvb = blockIdx.x, n = blockIdx.y;   // grid (100, 32), block 256
  const int tvl = threadIdx.x & 63, q = threadIdx.x >> 6;  // 4 quads of 16 cin
  const int tv = tvb * 64 + tvl;
  const float* xp = x + ((size_t)n * 64 + q * 16) * TV + tv;
  const float* mp = mask + ((size_t)n * 64 + q * 16) * TV + tv;
  u16 vals[16];
  float msacc = 0.f;
#pragma unroll
  for (int j = 0; j < 16; ++j) {                // coalesced: lanes = consecutive tv
    float xv = xp[(size_t)j * TV];
    float mv = mp[(size_t)j * TV];
    msacc += mv;
    vals[j] = f2bf(xv * mv);
  }
  uint4 lo, hi;
  lo.x = vals[0] | ((u32)vals[1] << 16);  lo.y = vals[2] | ((u32)vals[3] << 16);
  lo.z = vals[4] | ((u32)vals[5] << 16);  lo.w = vals[6] | ((u32)vals[7] << 16);
  hi.x = vals[8] | ((u32)vals[9] << 16);  hi.y = vals[10] | ((u32)vals[11] << 16);
  hi.z = vals[12] | ((u32)vals[13] << 16); hi.w = vals[14] | ((u32)vals[15] << 16);
  // chunk c8 = q*2 (vals 0-7) and q*2+1 (vals 8-15); lanes contiguous in tv
  *(uint4*)(xmT2 + (((size_t)n * 8 + q * 2) * NPADT + 100 + tv) * 8) = lo;
  *(uint4*)(xmT2 + (((size_t)n * 8 + q * 2 + 1) * NPADT + 100 + tv) * 8) = hi;
  __shared__ float red[4][64];
  red[q][tvl] = msacc;
  __syncthreads();
  if (q == 0) msum[n * TV + tv] = red[0][tvl] + red[1][tvl] + red[2][tvl] + red[3][tvl];
}

// ---- wb[kc][k=dt*64+cin], bf16, 16B-slot XOR pre-swizzle (by (kc>>1)&3) -----
__global__ void k_w(const float* __restrict__ weight, u16* __restrict__ wb) {
  int i = blockIdx.x * 256 + threadIdx.x;      // 110592
  if (i >= 110592) return;
  int kc = i / KDIM, k = i % KDIM;
  int cin = k & 63, dt = k >> 6;
  float v = weight[(kc * 64 + cin) * 9 + dt];
  int phys = (k & ~31) | ((((k >> 3) & 3) ^ ((kc >> 1) & 3)) << 3) | (k & 7);
  wb[kc * KDIM + phys] = f2bf(v);
}

// ---- per (n,t): upd -> s, mask_ratio, m_bool, Bc ----------------------------
__global__ void k_prep(const float* __restrict__ msum, const float* __restrict__ A_g,
                       float* __restrict__ s_ws, float* __restrict__ mr_ws,
                       float* __restrict__ mb_ws, float* __restrict__ Bc_ws) {
  int b = blockIdx.x;                          // 8192 = n*256 + t
  int n = b >> 8, t = b & 255;
  int tid = threadIdx.x;                       // 64
  __shared__ float uc[25];
  if (tid < 25) {
    float upd = 0.f;
    for (int dt = 0; dt < 9; ++dt) {
      int tt = t + dt - 4;
      if (tt >= 0 && tt < 256) upd += msum[n * TV + tt * 25 + tid];
    }
    float u_c = fminf(fmaxf(upd, 0.f), 1.f);
    float ratio = 576.f / (upd + 1e-8f);
    s_ws[n * TV + t * 25 + tid] = ratio * u_c * u_c;  // coeff of raw in out
    uc[tid] = u_c;
  }
  __syncthreads();
  if (tid < 25) {
    int w = tid;
    float M = 0.f;
    for (int k = 0; k < 3; ++k) {
      float acc = 0.f;
      for (int v = 0; v < 25; ++v) acc += uc[v] * A_g[(k * 25 + v) * 25 + w];
      Bc_ws[((size_t)(n * 3 + k) * 256 + t) * 25 + w] = acc;
      M += acc;
    }
    float mbv = (M != 0.f) ? 1.f : 0.f;
    mr_ws[n * TV + t * 25 + w] = mbv / (M + 1e-8f);
    mb_ws[n * TV + t * 25 + w] = mbv;
  }
}

// ---- implicit-GEMM: Cs[nl][kc][tv] = bf16( (W x im2col(xmT2)) * s ) ---------
// BM=96, BN=256, BK=32; 8 waves 2(M)x4(N); 3x4 MFMA tiles/wave.
// Depth-2 counted-vmcnt pipeline: 4-buffer LDS ring, one s_barrier per step.
__global__ __launch_bounds__(512, 2) void k_gemm(
    const u16* __restrict__ xmT2, const u16* __restrict__ wb,
    const float* __restrict__ s_g, u16* __restrict__ Cs, int n0) {
  __shared__ u16 Al[4][96 * 32];      // 24 KB
  __shared__ u16 Bl[4][4 * 256 * 8];  // 64 KB

  const int tid = threadIdx.x;
  const int bm = blockIdx.x, bn = blockIdx.y, nl = blockIdx.z;
  const int n = n0 + nl;
  const int tv0 = bn * 256;
  const int lane = tid & 63, wid = tid >> 6;
  const int wm = wid >> 2, wn = wid & 3;
  const int lrow = lane & 15, lgrp = lane >> 4;

  const u16* xmn = xmT2 + (size_t)n * 8 * NPADT * 8;

  f32x4 acc[3][4] = {};

  // 22 issues per K-step: 6 for A (96x32), 16 for B (4 cin-chunks x 4 col-groups)
  auto stage = [&](int buf, int ks) {
    const int dt = ks >> 1, cq = (ks & 1) * 4;
    const int shiftp = 100 + tv0 + (dt - 4) * 25;  // padded row index base
#pragma unroll
    for (int j = 0; j < 3; ++j) {
      int task = wid + j * 8;
      if (task >= 22) break;                       // wave-uniform
      if (task < 6) {
        int row = task * 16 + (lane >> 2), koff = (lane & 3) * 8;
        const u16* src = wb + (size_t)(bm * 96 + row) * KDIM + ks * 32 + koff;
        gload_lds16(src, &Al[buf][task * 512]);
      } else {
        int bt = task - 6;
        int g = bt >> 2, col = (bt & 3) * 64 + lane;
        // contiguous: consecutive lanes (tv) -> consecutive 16B
        const u16* src = xmn + ((size_t)(cq + g) * NPADT + shiftp + col) * 8;
        gload_lds16(src, &Bl[buf][bt * 512]);
      }
    }
  };

  stage(0, 0);
  stage(1, 1);

  for (int ks = 0; ks < 18; ++ks) {
    const int cur = ks & 3;
    if (ks < 16) stage((ks + 2) & 3, ks + 2);
    // wait for MY stage-ks loads: allow (loads/stage x stages-newer) in flight
    if (ks < 16) {
      if (wid < 6) VMCNT(6); else VMCNT(4);
    } else if (ks == 16) {
      if (wid < 6) VMCNT(3); else VMCNT(2);
    } else {
      VMCNT(0);
    }
    __builtin_amdgcn_s_barrier();      // all waves' stage-ks data now in LDS
    asm volatile("" ::: "memory");     // pin ds_reads behind the barrier

    short8 af[3], bfr[4];
#pragma unroll
    for (int rt = 0; rt < 3; ++rt) {
      int arow = wm * 48 + rt * 16 + lrow;
      af[rt] = *(const short8*)&Al[cur][arow * 32 + ((lgrp ^ ((arow >> 1) & 3)) << 3)];
    }
#pragma unroll
    for (int ct = 0; ct < 4; ++ct) {
      int bcol = wn * 64 + ct * 16 + lrow;
      bfr[ct] = *(const short8*)&Bl[cur][(lgrp * 256 + bcol) * 8];
    }
#pragma unroll
    for (int rt = 0; rt < 3; ++rt)
#pragma unroll
      for (int ct = 0; ct < 4; ++ct)
        acc[rt][ct] = __builtin_amdgcn_mfma_f32_16x16x32_bf16(af[rt], bfr[ct], acc[rt][ct], 0, 0, 0);
    // no trailing barrier: 4-ring keeps write buffers disjoint from read buffers
    // within the one-barrier skew window
  }

#pragma unroll
  for (int ct = 0; ct < 4; ++ct) {
    int colg = tv0 + wn * 64 + ct * 16 + lrow;
    float sv = s_g[n * TV + colg];
#pragma unroll
    for (int rt = 0; rt < 3; ++rt) {
      int rbase = bm * 96 + wm * 48 + rt * 16 + lgrp * 4;
#pragma unroll
      for (int r = 0; r < 4; ++r)
        Cs[(size_t)(nl * KC + rbase + r) * TV + colg] = f2bf(acc[rt][ct][r] * sv);
    }
  }
}

// ---- contraction: y = (sum_{k,v} Cs*A + sum_k bias*Bc) * mask_ratio ---------
// block = (tg of 8 t, nl); thread = (c, t_local), 25-w accumulator in VGPRs.
// Epilogue: y transposed through LDS (aliasing Cl) for coalesced 200-float
// runs; m_bool is c-independent -> direct broadcast coalesced stores.
__global__ __launch_bounds__(512) void k_contract(
    const u16* __restrict__ Cs, const float* __restrict__ A_g,
    const float* __restrict__ Bc_g, const float* __restrict__ mr_g,
    const float* __restrict__ mb_g, const float* __restrict__ bias_g,
    float* __restrict__ out, int n0) {
  __shared__ __align__(16) char sh_cl_ys[64 * 210 * 2];  // Cl u16[64][210] | Ys f32[32][201]
  u16  (*Cl)[210] = (u16(*)[210])sh_cl_ys;    // stride 105 dw, gcd(105,32)=1
  float (*Ys)[201] = (float(*)[201])sh_cl_ys; // stride 201, gcd(201,32)=1 -> conflict-free
  __shared__ float As[3][25][28];             // pad 25->28 for float4 reads
  __shared__ float Bcs[3][8][25];
  __shared__ float mrs[8][25];
  __shared__ float mbs[8][25];
  __shared__ float biass[192];

  const int tid = threadIdx.x;
  const int tg = blockIdx.x;                  // 0..31
  const int nl = blockIdx.y;
  const int n = n0 + nl;

  for (int i = tid; i < 3 * 25 * 28; i += 512) {
    int k = i / 700, r = (i % 700) / 28, w = i % 28;
    As[k][r][w] = (w < 25) ? A_g[(k * 25 + r) * 25 + w] : 0.f;
  }
  for (int i = tid; i < 600; i += 512) {
    int k = i / 200, t = (i % 200) / 25, w = i % 25;
    Bcs[k][t][w] = Bc_g[((size_t)(n * 3 + k) * 256 + tg * 8 + t) * 25 + w];
  }
  for (int i = tid; i < 200; i += 512) {
    mrs[i / 25][i % 25] = mr_g[n * TV + tg * 200 + i];
    mbs[i / 25][i % 25] = mb_g[n * TV + tg * 200 + i];
  }
  if (tid < 192) biass[tid] = bias_g[tid];

  const int c = tid & 63, tl = tid >> 6;
  f32x4 a4[7] = {};

  for (int k = 0; k < 3; ++k) {
    __syncthreads();
    for (int i = tid; i < 1600; i += 512) {   // 64 rows x 25 x 16B, uint4 global reads
      int row = i / 25, c8 = i % 25;
      const uint4 v = *(const uint4*)(Cs + (size_t)(nl * KC + k * 64 + row) * TV + tg * 200 + c8 * 8);
      u32* d = (u32*)&Cl[row][c8 * 8];
      d[0] = v.x; d[1] = v.y; d[2] = v.z; d[3] = v.w;
    }
    __syncthreads();
#pragma unroll 5
    for (int v = 0; v < 25; ++v) {
      float cs = bf2f(Cl[c][tl * 25 + v]);
      const f32x4* ar = (const f32x4*)&As[k][v][0];   // broadcast reads
#pragma unroll
      for (int q = 0; q < 7; ++q) a4[q] += cs * ar[q];
    }
  }

  // finalize per-thread y values
  float yv[25];
  {
    const float b0 = biass[c], b1 = biass[64 + c], b2 = biass[128 + c];
#pragma unroll
    for (int w = 0; w < 25; ++w) {
      float bt = b0 * Bcs[0][tl][w] + b1 * Bcs[1][tl][w] + b2 * Bcs[2][tl][w];
      yv[w] = (a4[w >> 2][w & 3] + bt) * mrs[tl][w];
    }
  }

  // y: two half-c passes through Ys (aliases Cl), then coalesced 200-float runs
  const size_t base_n = (size_t)(n * 64) * 6400 + tg * 200;
#pragma unroll
  for (int half = 0; half < 2; ++half) {
    __syncthreads();                       // Cl reads / prior Ys reads complete
    if ((c >> 5) == half) {
      float* yrow = &Ys[c & 31][tl * 25];
#pragma unroll
      for (int w = 0; w < 25; ++w) yrow[w] = yv[w];
    }
    __syncthreads();
    for (int i = tid; i < 6400; i += 512) {
      int ch = i / 200, j = i % 200;
      out[base_n + (size_t)(half * 32 + ch) * 6400 + j] = Ys[ch][j];
    }
  }

  // m_bool: c-independent broadcast, direct coalesced stores
  for (int i = tid; i < 12800; i += 512) {
    int cc = i / 200, j = i % 200;
    out[MB_OFF + base_n + (size_t)cc * 6400 + j] = mbs[j / 25][j % 25];
  }
}

extern "C" void kernel_launch(void* const* d_in, const int* in_sizes, int n_in,
                              void* d_out, int out_size, void* d_ws, size_t ws_size,
                              hipStream_t stream) {
  const float* x      = (const float*)d_in[0];
  const float* A      = (const float*)d_in[1];
  const float* mask   = (const float*)d_in[2];
  const float* weight = (const float*)d_in[3];
  const float* bias   = (const float*)d_in[4];
  float* out = (float*)d_out;
  char* ws = (char*)d_ws;

  u16*   xmT2  = (u16*)(ws);
  u16*   wb    = (u16*)(ws + OFF_WB);
  float* msum  = (float*)(ws + OFF_MSUM);
  float* s_ws  = (float*)(ws + OFF_S);
  float* mr_ws = (float*)(ws + OFF_MR);
  float* mb_ws = (float*)(ws + OFF_MB);
  float* Bc_ws = (float*)(ws + OFF_BC);
  u16*   Cs    = (u16*)(ws + OFF_CS);

  // chunk = samples of Cs that fit in remaining ws
  int chunk = 1;
  if (ws_size > (size_t)OFF_CS + CS_PER_N) {
    size_t c = (ws_size - OFF_CS) / CS_PER_N;
    chunk = (c > 32) ? 32 : (int)c;
  }

  k_pad<<<200, 256, 0, stream>>>(xmT2);
  k_xmT<<<dim3(100, 32), 256, 0, stream>>>(x, mask, xmT2, msum);
  k_w<<<432, 256, 0, stream>>>(weight, wb);
  k_prep<<<8192, 64, 0, stream>>>(msum, A, s_ws, mr_ws, mb_ws, Bc_ws);

  hipMemcpyAsync(out + Y_SIZE, A, 1875 * sizeof(float),
                 hipMemcpyDeviceToDevice, stream);

  for (int done = 0; done < 32;) {
    int g = (32 - done < chunk) ? (32 - done) : chunk;
    k_gemm<<<dim3(2, 25, g), 512, 0, stream>>>(xmT2, wb, s_ws, Cs, done);
    k_contract<<<dim3(32, g), 512, 0, stream>>>(Cs, A, Bc_ws, mr_ws, mb_ws, bias,
                                                out, done);
    done += g;
  }
}

// Round 6
// 184.984 us; speedup vs baseline: 2.2410x; 1.1781x over previous
//
#include <hip/hip_runtime.h>

// PartialGConv: partial temporal conv (TK=9, pad 4) + mask-ratio + graph einsum.
// FUSED: one kernel does bf16 implicit-GEMM (MFMA 16x16x32, BM=192 x BN=200(8t)
// x K=576) AND the (k,v)-contraction epilogue through LDS — no Cs intermediate.
//
// ws layout (bytes):
//   xmT2 u16[32][8][6656][8] @0          x*mask bf16, cin-chunk-major, padded rows
//   wb   u16[192][576]      @27,262,976 weights bf16, k=dt*64+cin, 16B-slot swizzled
//   msum f32[32][6400]      @27,484,160 sum_cin mask
//   s    f32[32][6400]      @28,303,360 576/(upd+eps)*uc^2
//   mr   f32[32][6400]      @29,122,560 mask_ratio
//   mb   f32[32][6400]      @29,941,760 m_bool
//   Bc   f32[32][3][256][25]@30,760,960 sum_v uc*A[k,v,w]

typedef unsigned short u16;
typedef unsigned int u32;
typedef short short8 __attribute__((ext_vector_type(8)));
typedef float f32x4 __attribute__((ext_vector_type(4)));

#define TV 6400
#define KC 192
#define KDIM 576
#define NPADT 6656          // 100 front pad + 6400 + 156 back pad
#define Y_SIZE 13107200
#define MB_OFF 13109075     // Y_SIZE + 1875

#define OFF_WB   27262976
#define OFF_MSUM 27484160
#define OFF_S    28303360
#define OFF_MR   29122560
#define OFF_MB   29941760
#define OFF_BC   30760960

#define VMCNT(N) asm volatile("s_waitcnt vmcnt(" #N ")" ::: "memory")

__device__ __forceinline__ u16 f2bf(float f) {
  u32 u = __builtin_bit_cast(u32, f);
  u = (u + 0x7FFFu + ((u >> 16) & 1u)) >> 16;   // RTNE
  return (u16)u;
}
__device__ __forceinline__ float bf2f(u16 h) {
  return __builtin_bit_cast(float, (u32)h << 16);
}
__device__ __forceinline__ void gload_lds16(const u16* g, u16* l) {
  __builtin_amdgcn_global_load_lds(
      (const __attribute__((address_space(1))) u32*)(const void*)g,
      (__attribute__((address_space(3))) u32*)(void*)l, 16, 0, 0);
}

// ---- zero the temporal pad rows of xmT2 -------------------------------------
__global__ void k_pad(u16* __restrict__ xmT2) {
  int i = blockIdx.x * 256 + threadIdx.x;       // 65536 uint4
  if (i >= 65536) return;
  int n = i >> 11, r = i & 2047;                // 8 chunks x 256 pad rows
  int c8 = r >> 8, row = r & 255;
  int tvrow = (row < 100) ? row : (6400 + row); // front 0..99 / back 6500..6655
  uint4 z; z.x = z.y = z.z = z.w = 0u;
  *(uint4*)(xmT2 + (((size_t)n * 8 + c8) * NPADT + tvrow) * 8) = z;
}

// ---- xmT2 = bf16(x*mask) cin-chunk-major + msum = sum_cin mask --------------
__global__ void k_xmT(const float* __restrict__ x, const float* __restrict__ mask,
                      u16* __restrict__ xmT2, float* __restrict__ msum) {
  const int tvb = blockIdx.x, n = blockIdx.y;   // grid (100, 32), block 256
  const int tvl = threadIdx.x & 63, q = threadIdx.x >> 6;  // 4 quads of 16 cin
  const int tv = tvb * 64 + tvl;
  const float* xp = x + ((size_t)n * 64 + q * 16) * TV + tv;
  const float* mp = mask + ((size_t)n * 64 + q * 16) * TV + tv;
  u16 vals[16];
  float msacc = 0.f;
#pragma unroll
  for (int j = 0; j < 16; ++j) {                // coalesced: lanes = consecutive tv
    float xv = xp[(size_t)j * TV];
    float mv = mp[(size_t)j * TV];
    msacc += mv;
    vals[j] = f2bf(xv * mv);
  }
  uint4 lo, hi;
  lo.x = vals[0] | ((u32)vals[1] << 16);  lo.y = vals[2] | ((u32)vals[3] << 16);
  lo.z = vals[4] | ((u32)vals[5] << 16);  lo.w = vals[6] | ((u32)vals[7] << 16);
  hi.x = vals[8] | ((u32)vals[9] << 16);  hi.y = vals[10] | ((u32)vals[11] << 16);
  hi.z = vals[12] | ((u32)vals[13] << 16); hi.w = vals[14] | ((u32)vals[15] << 16);
  *(uint4*)(xmT2 + (((size_t)n * 8 + q * 2) * NPADT + 100 + tv) * 8) = lo;
  *(uint4*)(xmT2 + (((size_t)n * 8 + q * 2 + 1) * NPADT + 100 + tv) * 8) = hi;
  __shared__ float red[4][64];
  red[q][tvl] = msacc;
  __syncthreads();
  if (q == 0) msum[n * TV + tv] = red[0][tvl] + red[1][tvl] + red[2][tvl] + red[3][tvl];
}

// ---- wb[kc][k=dt*64+cin], bf16, 16B-slot XOR pre-swizzle (by (kc>>1)&3) -----
__global__ void k_w(const float* __restrict__ weight, u16* __restrict__ wb) {
  int i = blockIdx.x * 256 + threadIdx.x;      // 110592
  if (i >= 110592) return;
  int kc = i / KDIM, k = i % KDIM;
  int cin = k & 63, dt = k >> 6;
  float v = weight[(kc * 64 + cin) * 9 + dt];
  int phys = (k & ~31) | ((((k >> 3) & 3) ^ ((kc >> 1) & 3)) << 3) | (k & 7);
  wb[kc * KDIM + phys] = f2bf(v);
}

// ---- per (n,t): upd -> s, mask_ratio, m_bool, Bc ----------------------------
__global__ void k_prep(const float* __restrict__ msum, const float* __restrict__ A_g,
                       float* __restrict__ s_ws, float* __restrict__ mr_ws,
                       float* __restrict__ mb_ws, float* __restrict__ Bc_ws) {
  int b = blockIdx.x;                          // 8192 = n*256 + t
  int n = b >> 8, t = b & 255;
  int tid = threadIdx.x;                       // 64
  __shared__ float uc[25];
  if (tid < 25) {
    float upd = 0.f;
    for (int dt = 0; dt < 9; ++dt) {
      int tt = t + dt - 4;
      if (tt >= 0 && tt < 256) upd += msum[n * TV + tt * 25 + tid];
    }
    float u_c = fminf(fmaxf(upd, 0.f), 1.f);
    float ratio = 576.f / (upd + 1e-8f);
    s_ws[n * TV + t * 25 + tid] = ratio * u_c * u_c;  // coeff of raw in out
    uc[tid] = u_c;
  }
  __syncthreads();
  if (tid < 25) {
    int w = tid;
    float M = 0.f;
    for (int k = 0; k < 3; ++k) {
      float acc = 0.f;
      for (int v = 0; v < 25; ++v) acc += uc[v] * A_g[(k * 25 + v) * 25 + w];
      Bc_ws[((size_t)(n * 3 + k) * 256 + t) * 25 + w] = acc;
      M += acc;
    }
    float mbv = (M != 0.f) ? 1.f : 0.f;
    mr_ws[n * TV + t * 25 + w] = mbv / (M + 1e-8f);
    mb_ws[n * TV + t * 25 + w] = mbv;
  }
}

// ---- FUSED: implicit-GEMM + (k,v)-contraction + coalesced epilogue ----------
// Block (tg, n): BM=192 (all kc), BN=200 useful / 256 staged, BK=32, 18 steps.
// 8 waves = 4(M) x 2(N): wave rows wm*48 (3 frags), cols wn? {0-111:7f, 112-207:6f}.
// 2-ring LDS (56KB) + 14KB misc -> 2 blocks/CU; VGPR capped 128 via bounds.
__global__ __launch_bounds__(512, 4) void k_fused(
    const u16* __restrict__ xmT2, const u16* __restrict__ wb,
    const float* __restrict__ s_g, const float* __restrict__ A_g,
    const float* __restrict__ Bc_g, const float* __restrict__ mr_g,
    const float* __restrict__ mb_g, const float* __restrict__ bias_g,
    float* __restrict__ out) {
  __shared__ __align__(16) char ring[57344];  // A 2x12KB @0 | B 2x16KB @24576
                                              // epilogue alias: Cl u16[64][210], Ys f32[32][201]
  __shared__ float As[3][25][28];             // pad 25->28 for float4 reads
  __shared__ float Bcs[3][8][25];
  __shared__ float mrs[8][25];
  __shared__ float mbs[8][25];
  __shared__ float biass[192];
  __shared__ float ss[200];

  const int tid = threadIdx.x;
  const int tg = blockIdx.x;                  // 0..31 (8-t group)
  const int n = blockIdx.y;                   // 0..31
  const int tv0 = tg * 200;
  const int lane = tid & 63, wid = tid >> 6;
  const int wm = wid >> 1, wn = wid & 1;
  const int lrow = lane & 15, lgrp = lane >> 4;
  const int nf = 7 - wn, colb = wn * 112;

  const u16* xmn = xmT2 + (size_t)n * 8 * NPADT * 8;

  // misc preloads (epilogue-only data; visibility via first loop barrier)
  for (int i = tid; i < 2100; i += 512) {
    int k = i / 700, r = (i % 700) / 28, w = i % 28;
    As[k][r][w] = (w < 25) ? A_g[(k * 25 + r) * 25 + w] : 0.f;
  }
  for (int i = tid; i < 600; i += 512) {
    int k = i / 200, t = (i % 200) / 25, w = i % 25;
    Bcs[k][t][w] = Bc_g[((size_t)(n * 3 + k) * 256 + tg * 8 + t) * 25 + w];
  }
  for (int i = tid; i < 200; i += 512) {
    mrs[i / 25][i % 25] = mr_g[n * TV + tv0 + i];
    mbs[i / 25][i % 25] = mb_g[n * TV + tv0 + i];
    ss[i] = s_g[n * TV + tv0 + i];
  }
  if (tid < 192) biass[tid] = bias_g[tid];

  f32x4 acc[3][7] = {};

  // 28 issues/step: A 12 (192 rows x 32k), B 16 (4 cin-chunks x 4 col-groups of 64)
  auto stage = [&](int buf, int ks) {
    const int dt = ks >> 1, cq = (ks & 1) * 4;
    const int shiftp = 100 + tv0 + (dt - 4) * 25;
    u16* abase = (u16*)(ring + buf * 12288);
    u16* bbase = (u16*)(ring + 24576 + buf * 16384);
#pragma unroll
    for (int j = 0; j < 4; ++j) {
      int task = wid + j * 8;
      if (task >= 28) break;                       // wave-uniform
      if (task < 12) {
        const u16* src = wb + (size_t)(task * 16 + (lane >> 2)) * KDIM + ks * 32 + (lane & 3) * 8;
        gload_lds16(src, abase + task * 512);
      } else {
        int bt = task - 12;
        const u16* src = xmn + ((size_t)(cq + (bt >> 2)) * NPADT + shiftp + (bt & 3) * 64 + lane) * 8;
        gload_lds16(src, bbase + bt * 512);
      }
    }
  };

  stage(0, 0);

  for (int ks = 0; ks < 18; ++ks) {
    const int cur = ks & 1;
    VMCNT(0);                          // own stage-ks loads landed
    __builtin_amdgcn_s_barrier();      // all waves' stage-ks in LDS; prev reads done
    asm volatile("" ::: "memory");
    if (ks < 17) stage(cur ^ 1, ks + 1);   // post-barrier: buf cur^1 safe to overwrite

    const u16* abuf = (const u16*)(ring + cur * 12288);
    const u16* bbuf = (const u16*)(ring + 24576 + cur * 16384);
    short8 af[3];
#pragma unroll
    for (int m = 0; m < 3; ++m) {
      int arow = wm * 48 + m * 16 + lrow;
      af[m] = *(const short8*)&abuf[arow * 32 + ((lgrp ^ ((arow >> 1) & 3)) << 3)];
    }
#pragma unroll
    for (int ct = 0; ct < 7; ++ct) {
      if (ct < nf) {
        int bcol = colb + ct * 16 + lrow;
        short8 bfr = *(const short8*)&bbuf[(lgrp * 256 + bcol) * 8];
#pragma unroll
        for (int m = 0; m < 3; ++m)
          acc[m][ct] = __builtin_amdgcn_mfma_f32_16x16x32_bf16(af[m], bfr, acc[m][ct], 0, 0, 0);
      }
    }
  }

  // ---- epilogue: per-k Cl (s-scaled bf16) -> VALU contraction with A -------
  u16 (*Cl)[210] = (u16(*)[210])ring;          // stride 105 dw, gcd(105,32)=1
  float (*Ys)[201] = (float(*)[201])ring;      // alias, barrier-separated lifetime
  const int c = tid & 63, tl = tid >> 6;
  f32x4 a4[7] = {};

  for (int k = 0; k < 3; ++k) {
    __syncthreads();                           // ring reads / prev Cl reads done
#pragma unroll
    for (int m = 0; m < 3; ++m) {
      int R = wm * 48 + m * 16 + lgrp * 4;
      if ((R >> 6) == k) {
#pragma unroll
        for (int ct = 0; ct < 7; ++ct) {
          if (ct < nf) {
            int col = colb + ct * 16 + lrow;
            if (col < 200) {
#pragma unroll
              for (int r = 0; r < 4; ++r)
                Cl[(R & 63) + r][col] = f2bf(acc[m][ct][r] * ss[col]);
            }
          }
        }
      }
    }
    __syncthreads();
#pragma unroll 5
    for (int v = 0; v < 25; ++v) {
      float cs = bf2f(Cl[c][tl * 25 + v]);
      const f32x4* ar = (const f32x4*)&As[k][v][0];   // broadcast reads
#pragma unroll
      for (int q = 0; q < 7; ++q) a4[q] += cs * ar[q];
    }
  }

  // finalize per-thread y values
  float yv[25];
  {
    const float b0 = biass[c], b1 = biass[64 + c], b2 = biass[128 + c];
#pragma unroll
    for (int w = 0; w < 25; ++w) {
      float bt = b0 * Bcs[0][tl][w] + b1 * Bcs[1][tl][w] + b2 * Bcs[2][tl][w];
      yv[w] = (a4[w >> 2][w & 3] + bt) * mrs[tl][w];
    }
  }

  // y: two half-c passes through Ys (aliases Cl), coalesced 200-float runs
  const size_t base_n = (size_t)(n * 64) * 6400 + tv0;
#pragma unroll
  for (int half = 0; half < 2; ++half) {
    __syncthreads();                       // Cl/prior-Ys reads complete
    if ((c >> 5) == half) {
      float* yrow = &Ys[c & 31][tl * 25];
#pragma unroll
      for (int w = 0; w < 25; ++w) yrow[w] = yv[w];
    }
    __syncthreads();
    for (int i = tid; i < 6400; i += 512) {
      int ch = i / 200, j = i % 200;
      out[base_n + (size_t)(half * 32 + ch) * 6400 + j] = Ys[ch][j];
    }
  }

  // m_bool: c-independent broadcast, direct coalesced stores
  for (int i = tid; i < 12800; i += 512) {
    int cc = i / 200, j = i % 200;
    out[MB_OFF + base_n + (size_t)cc * 6400 + j] = mbs[j / 25][j % 25];
  }
}

extern "C" void kernel_launch(void* const* d_in, const int* in_sizes, int n_in,
                              void* d_out, int out_size, void* d_ws, size_t ws_size,
                              hipStream_t stream) {
  const float* x      = (const float*)d_in[0];
  const float* A      = (const float*)d_in[1];
  const float* mask   = (const float*)d_in[2];
  const float* weight = (const float*)d_in[3];
  const float* bias   = (const float*)d_in[4];
  float* out = (float*)d_out;
  char* ws = (char*)d_ws;

  u16*   xmT2  = (u16*)(ws);
  u16*   wb    = (u16*)(ws + OFF_WB);
  float* msum  = (float*)(ws + OFF_MSUM);
  float* s_ws  = (float*)(ws + OFF_S);
  float* mr_ws = (float*)(ws + OFF_MR);
  float* mb_ws = (float*)(ws + OFF_MB);
  float* Bc_ws = (float*)(ws + OFF_BC);

  k_pad<<<256, 256, 0, stream>>>(xmT2);
  k_xmT<<<dim3(100, 32), 256, 0, stream>>>(x, mask, xmT2, msum);
  k_w<<<432, 256, 0, stream>>>(weight, wb);
  k_prep<<<8192, 64, 0, stream>>>(msum, A, s_ws, mr_ws, mb_ws, Bc_ws);

  hipMemcpyAsync(out + Y_SIZE, A, 1875 * sizeof(float),
                 hipMemcpyDeviceToDevice, stream);

  k_fused<<<dim3(32, 32), 512, 0, stream>>>(xmT2, wb, s_ws, A, Bc_ws, mr_ws,
                                            mb_ws, bias, out);
}